// Round 3
// baseline (1757.726 us; speedup 1.0000x reference)
//
#include <hip/hip_runtime.h>
#include <cstdint>
#include <cstddef>
#include <math.h>

#define DEV __device__ __forceinline__

// ---------- constants ----------
// B=8, S=4096, D=1024, DC=1024, H=16, L=2, TOPK=2, MAX_DEPTH=32, EPS=1e-5
// ALL array inputs are FP32 (reference uses jnp.float32 throughout). Output FP32.

typedef short s8v __attribute__((ext_vector_type(8)));   // 8 bf16 (4 VGPRs)
typedef float f4v __attribute__((ext_vector_type(4)));   // MFMA acc

DEV float geluf(float x) { return 0.5f * x * (1.0f + erff(x * 0.70710678118654752440f)); }
DEV double gelud(double x) { return 0.5 * x * (1.0 + erf(x * 0.70710678118654752440)); }
DEV unsigned short f2us(float f) {          // fp32 -> bf16 RNE
    unsigned u = __float_as_uint(f);
    u += 0x7fffu + ((u >> 16) & 1u);
    return (unsigned short)(u >> 16);
}

DEV void gload16(const void* g, void* l) {
    __builtin_amdgcn_global_load_lds(
        (const __attribute__((address_space(1))) void*)g,
        (__attribute__((address_space(3))) void*)l, 16, 0, 0);
}

DEV void blockReduce2d(double& a, double& b, double* lds /*>=8 doubles*/) {
    __syncthreads();
#pragma unroll
    for (int off = 32; off >= 1; off >>= 1) {
        a += __shfl_xor(a, off, 64);
        b += __shfl_xor(b, off, 64);
    }
    int w = threadIdx.x >> 6;
    if ((threadIdx.x & 63) == 0) { lds[w] = a; lds[4 + w] = b; }
    __syncthreads();
    a = lds[0] + lds[1] + lds[2] + lds[3];
    b = lds[4] + lds[5] + lds[6] + lds[7];
    __syncthreads();
}

// ---------------------------------------------------------------------------
// 1) pool pass: per-token LN stats over D=1024 (double); accumulate
//    sum_s (x-mu)*istd per (b,d) into Macc (double atomics); store per-token
//    (sumX, sumX^2) double pairs. Also (if XH/XL non-null) emit the bf16
//    truncation hi/lo split of X for the bf16-A router.
// ---------------------------------------------------------------------------
__global__ __launch_bounds__(256) void pool_kernel(
    const float* __restrict__ X, double* __restrict__ Macc,
    double* __restrict__ tokstats,
    unsigned short* __restrict__ XH, unsigned short* __restrict__ XL)
{
    int b = blockIdx.y;
    int w = threadIdx.x >> 6, l = threadIdx.x & 63;
    int s0 = blockIdx.x * 64 + w * 16;
    double acc[16];
#pragma unroll
    for (int e = 0; e < 16; e++) acc[e] = 0.0;
    __shared__ double red[4][1024];

    for (int t = 0; t < 16; t++) {
        int s = s0 + t;
        const float* row = X + (size_t)(b * 4096 + s) * 1024;
        float xv[16];
#pragma unroll
        for (int m = 0; m < 16; m++) xv[m] = row[l + 64 * m];
        if (XH) {
            size_t base = (size_t)(b * 4096 + s) * 1024 + l;
#pragma unroll
            for (int m = 0; m < 16; m++) {
                unsigned u = __float_as_uint(xv[m]);
                XH[base + 64 * m] = (unsigned short)(u >> 16);
                float r = xv[m] - __uint_as_float(u & 0xffff0000u);
                XL[base + 64 * m] = (unsigned short)(__float_as_uint(r) >> 16);
            }
        }
        double s1 = 0.0, s2 = 0.0;
#pragma unroll
        for (int m = 0; m < 16; m++) { double x = (double)xv[m]; s1 += x; s2 += x * x; }
#pragma unroll
        for (int off = 32; off >= 1; off >>= 1) {
            s1 += __shfl_xor(s1, off, 64);
            s2 += __shfl_xor(s2, off, 64);
        }
        double mu = s1 * (1.0 / 1024.0);
        double var = s2 * (1.0 / 1024.0) - mu * mu;
        double istd = 1.0 / sqrt(var + 1e-5);
        if (l == 0) {
            tokstats[(size_t)(b * 4096 + s) * 2]     = s1;
            tokstats[(size_t)(b * 4096 + s) * 2 + 1] = s2;
        }
#pragma unroll
        for (int m = 0; m < 16; m++) acc[m] += ((double)xv[m] - mu) * istd;
    }
#pragma unroll
    for (int m = 0; m < 16; m++) red[w][l + 64 * m] = acc[m];
    __syncthreads();
    for (int d = threadIdx.x; d < 1024; d += 256)
        atomicAdd(&Macc[b * 1024 + d], red[0][d] + red[1][d] + red[2][d] + red[3][d]);
}

// ---------------------------------------------------------------------------
// 2) prep: sigma schedule + sinusoidal embedding (double), z -> double
// ---------------------------------------------------------------------------
__global__ void prep_kernel(const int* __restrict__ step_idx,
                            const float* __restrict__ z,
                            double* __restrict__ emb, double* __restrict__ z0)
{
    int step = step_idx[0];
    if (step > 31) step = 31;
    double t = (double)step / 31.0;
    double sig = cos(t * 1.5707963267948966);
    if (sig < 1e-4) sig = 1e-4;
    for (int k = threadIdx.x; k < 512; k += 256) {
        double fr = exp(-9.210340371976184 * ((double)k / 512.0));
        double a = sig * fr;
        emb[k] = cos(a);
        emb[512 + k] = sin(a);
    }
    for (int i = threadIdx.x; i < 8192; i += 256) z0[i] = (double)z[i];
}

// ---------------------------------------------------------------------------
// 3) prepw: WThi/WTlo[j][i] = bf16 hi/lo split of gr[i]*Wr1[i][j], i<1024,
//    transposed for MFMA B-operand.
// ---------------------------------------------------------------------------
__global__ __launch_bounds__(256) void prepw_kernel(
    const float* __restrict__ Wr1, const float* __restrict__ gr,
    unsigned short* __restrict__ WThi, unsigned short* __restrict__ WTlo)
{
    __shared__ unsigned short th[64][65], tl[64][65];
    int tx = threadIdx.x & 63, ty = threadIdx.x >> 6;
    int i0 = blockIdx.y * 64, j0 = blockIdx.x * 64;
#pragma unroll 4
    for (int k = 0; k < 16; k++) {
        int row = ty * 16 + k;
        float w = (float)((double)gr[i0 + row] * (double)Wr1[(size_t)(i0 + row) * 1024 + j0 + tx]);
        unsigned short hi = f2us(w);
        float hif = __uint_as_float((unsigned)hi << 16);
        unsigned short lo = f2us(w - hif);
        th[row][tx] = hi;
        tl[row][tx] = lo;
    }
    __syncthreads();
#pragma unroll 4
    for (int k = 0; k < 16; k++) {
        int row = ty * 16 + k;
        WThi[(size_t)(j0 + row) * 1024 + i0 + tx] = th[tx][row];
        WTlo[(size_t)(j0 + row) * 1024 + i0 + tx] = tl[tx][row];
    }
}

// ---------------------------------------------------------------------------
// 4) column sums over all 2048 rows (double, k-split + atomics):
//    C[j] = sum gr_i*W_ij ; hb[j] = sum br_i*W_ij + br1[j]
// ---------------------------------------------------------------------------
__global__ __launch_bounds__(256) void colsum_kernel(
    const float* __restrict__ Wr1, const float* __restrict__ gr,
    const float* __restrict__ br, const float* __restrict__ br1,
    double* __restrict__ Cvec, double* __restrict__ hbvec)
{
    int j = blockIdx.x * 256 + threadIdx.x;
    int i0 = blockIdx.y * 128;
    double c = 0.0, bw = 0.0;
#pragma unroll 4
    for (int k = 0; k < 128; k++) {
        int i = i0 + k;
        double wv = (double)Wr1[(size_t)i * 1024 + j];
        c += (double)gr[i] * wv;
        bw += (double)br[i] * wv;
    }
    if (blockIdx.y == 0) bw += (double)br1[j];
    atomicAdd(&Cvec[j], c);
    atomicAdd(&hbvec[j], bw);
}

// ---------------------------------------------------------------------------
// 5) generic small-M GEMM (double accumulation), K-split over grid.y with
//    double atomicAdd outputs. IN modes fold the previous op's epilogue.
// ---------------------------------------------------------------------------
template <int IN, int R>
__global__ __launch_bounds__(256) void gemvd_kernel(
    const float* __restrict__ W, int K, int N, int kchunk, int kstr,
    const double* __restrict__ in0, const double* __restrict__ in1,
    const double* __restrict__ in2,
    const float* __restrict__ ba0, const float* __restrict__ ba1,
    double* __restrict__ out)
{
    const int CH = 64;
    __shared__ double xin[R][CH];
    int tid = threadIdx.x;
    int j = blockIdx.x * 256 + tid;
    int kbeg = blockIdx.y * kchunk;
    double acc[R];
#pragma unroll
    for (int r = 0; r < R; r++) acc[r] = 0.0;

    for (int k0 = kbeg; k0 < kbeg + kchunk; k0 += CH) {
        for (int idx = tid; idx < R * CH; idx += 256) {
            int r = idx / CH, ii = idx % CH, i = k0 + ii;
            double v;
            if (IN == 0) {
                v = in0[(size_t)r * kstr + i] + (ba0 ? (double)ba0[i] : 0.0);
            } else if (IN == 1) {            // pooled-mean -> g (affine LN params)
                v = (double)ba0[i] * (in0[(size_t)r * kstr + i] * (1.0 / 4096.0)) + (double)ba1[i];
            } else if (IN == 2) {            // gelu(prev + bias)
                v = gelud(in0[(size_t)r * kstr + i] + (ba0 ? (double)ba0[i] : 0.0));
            } else if (IN == 3) {            // adaLN: ln(z)*(1+s1)+sh1
                double mu = in1[r * 2], istd = in1[r * 2 + 1];
                double s1 = in2[(size_t)r * 4096 + i] + (double)ba0[i];
                double sh1 = in2[(size_t)r * 4096 + 1024 + i] + (double)ba0[1024 + i];
                v = (in0[(size_t)r * 1024 + i] - mu) * istd * (1.0 + s1) + sh1;
            } else {                         // IN==4: concat(x_ctrl+b_inp, t_embed+bt2)
                v = (i < 1024) ? (in0[(size_t)r * 1024 + i] + (double)ba0[i])
                               : (in1[i - 1024] + (double)ba1[i - 1024]);
            }
            xin[r][ii] = v;
        }
        __syncthreads();
#pragma unroll 16
        for (int kk = 0; kk < CH; kk++) {
            double wv = (double)W[(size_t)(k0 + kk) * N + j];
#pragma unroll
            for (int r = 0; r < R; r++) acc[r] += xin[r][kk] * wv;
        }
        __syncthreads();
    }
#pragma unroll
    for (int r = 0; r < R; r++) atomicAdd(&out[(size_t)r * N + j], acc[r]);
}

// ---------------------------------------------------------------------------
// 6) per-row (8) stats: mu, istd (double)
// ---------------------------------------------------------------------------
__global__ void stats8_kernel(const double* __restrict__ z, double* __restrict__ zstats)
{
    __shared__ double lds[8];
    int r = blockIdx.x, tid = threadIdx.x;
    double s = 0.0, ss = 0.0;
    for (int i = tid; i < 1024; i += 256) {
        double v = z[(size_t)r * 1024 + i];
        s += v; ss += v * v;
    }
    blockReduce2d(s, ss, lds);
    if (tid == 0) {
        double mu = s * (1.0 / 1024.0);
        double var = ss * (1.0 / 1024.0) - mu * mu;
        zstats[r * 2] = mu;
        zstats[r * 2 + 1] = 1.0 / sqrt(var + 1e-5);
    }
}

// ---------------------------------------------------------------------------
// 7) residual epilogue of a denoise block + stats of new z (double)
// ---------------------------------------------------------------------------
__global__ void resid_kernel(const double* __restrict__ zc, const double* __restrict__ h2pre,
                             const float* __restrict__ bm2,
                             const double* __restrict__ modpre,
                             const float* __restrict__ bmod,
                             double* __restrict__ znew, double* __restrict__ zstats)
{
    __shared__ double lds[8];
    int r = blockIdx.x, tid = threadIdx.x;
    double s = 0.0, ss = 0.0;
#pragma unroll
    for (int c = 0; c < 4; c++) {
        int i = tid + c * 256;
        double s2 = modpre[(size_t)r * 4096 + 2048 + i] + (double)bmod[2048 + i];
        double sh2 = modpre[(size_t)r * 4096 + 3072 + i] + (double)bmod[3072 + i];
        double h = h2pre[(size_t)r * 1024 + i] + (double)bm2[i];
        double v = zc[(size_t)r * 1024 + i] + h * (1.0 + s2) + sh2;
        znew[(size_t)r * 1024 + i] = v;
        s += v; ss += v * v;
    }
    blockReduce2d(s, ss, lds);
    if (tid == 0) {
        double mu = s * (1.0 / 1024.0);
        double var = ss * (1.0 / 1024.0) - mu * mu;
        zstats[r * 2] = mu;
        zstats[r * 2 + 1] = 1.0 / sqrt(var + 1e-5);
    }
}

// ---------------------------------------------------------------------------
// 8) final z LN (gz,bz affine) -> zv (= z_final*gr_z) + router z-part sums
// ---------------------------------------------------------------------------
__global__ void zfinal_kernel(const double* __restrict__ zfpre,
                              const float* __restrict__ bfb,
                              const float* __restrict__ gz,
                              const float* __restrict__ bz,
                              const float* __restrict__ gr,
                              double* __restrict__ zv, double* __restrict__ zrstats)
{
    __shared__ double xb[1024];
    __shared__ double lds[8];
    int r = blockIdx.x, tid = threadIdx.x;
    double s = 0.0, ss = 0.0;
#pragma unroll
    for (int c = 0; c < 4; c++) {
        int i = tid + c * 256;
        double x = zfpre[(size_t)r * 1024 + i] + (double)bfb[i];
        xb[i] = x;
        s += x; ss += x * x;
    }
    blockReduce2d(s, ss, lds);
    double mu = s * (1.0 / 1024.0);
    double var = ss * (1.0 / 1024.0) - mu * mu;
    double istd = 1.0 / sqrt(var + 1e-5);
    double s2 = 0.0, s2s = 0.0;
#pragma unroll
    for (int c = 0; c < 4; c++) {
        int i = tid + c * 256;
        double zf = (xb[i] - mu) * istd * (double)gz[i] + (double)bz[i];
        zv[(size_t)r * 1024 + i] = zf * (double)gr[1024 + i];
        s2 += zf; s2s += zf * zf;
    }
    blockReduce2d(s2, s2s, lds);
    if (tid == 0) { zrstats[r * 2] = s2; zrstats[r * 2 + 1] = s2s; }
}

// ---------------------------------------------------------------------------
// 9a) router stage A v3: G = X @ (gr.Wr1_x)^T, 3-term bf16 MFMA.
//     - hi streams (Ah,Bh): global_load_lds, 2-phase double-buffered,
//       ONE barrier per k-step (stage next tile before computing current).
//     - lo streams (Al,Bl): single-use -> direct global->VGPR fragment loads,
//       no LDS, no barrier coupling.
//     - LDS exactly 32KB (2x8K Ah + 2x8K Bh), union'd with a 4-pass
//       32-column epilogue; LN stats recomputed from global in epilogue.
//     - XCD-chunked 1D grid for L2 locality.
// ---------------------------------------------------------------------------
__global__ __launch_bounds__(256) void router3_kernel(
    const unsigned short* __restrict__ XH, const unsigned short* __restrict__ XL,
    const unsigned short* __restrict__ WThi, const unsigned short* __restrict__ WTlo,
    const double* __restrict__ tokstats, const double* __restrict__ zrstats,
    const double* __restrict__ Vmat, const double* __restrict__ Cvec,
    const double* __restrict__ hbvec, const float* __restrict__ Wr2,
    float* __restrict__ logits)
{
    __shared__ union {
        unsigned short hb[16384];                         // [A0|A1|B0|B1] 4x8KB
        struct { float Ht[32 * 133]; float W2[512]; } e;  // 19KB epilogue
    } sm;

    const int tid = threadIdx.x;
    // XCD-chunked mapping: 2048 blocks, 8 n-tiles of one token tile adjacent
    // on the same XCD.
    const int id = blockIdx.x;
    const int xcd = id & 7, local = id >> 3;
    const int tokTile = xcd * 32 + (local >> 3);
    const int nTile = local & 7;
    const int n0 = nTile * 128, tok0 = tokTile * 128;
    const int b = tok0 >> 12;

    const int l = tid & 63, wid = tid >> 6;
    const int wm = wid >> 1, wn = wid & 1;
    const int lr = l & 15, q = l >> 4;

    // hi staging: 2 chunks per stream per thread (8KB per stream per step)
    const unsigned short *gA[2], *gB[2];
    int ldst[2];
#pragma unroll
    for (int it = 0; it < 2; it++) {
        int c = it * 256 + tid;
        int m = c >> 2, p = (c & 3) ^ ((m >> 1) & 3);
        gA[it] = XH + (size_t)(tok0 + m) * 1024 + p * 8;
        gB[it] = WThi + (size_t)(n0 + m) * 1024 + p * 8;
        ldst[it] = c * 16;
    }

    int aoff[4], boff[4];
    const unsigned short *pAlo[4], *pBlo[4];
#pragma unroll
    for (int i = 0; i < 4; i++) {
        int ra = wm * 64 + i * 16 + lr;
        aoff[i] = ra * 32 + ((q ^ ((ra >> 1) & 3)) << 3);
        int rb = wn * 64 + i * 16 + lr;
        boff[i] = rb * 32 + ((q ^ ((rb >> 1) & 3)) << 3);
        pAlo[i] = XL + (size_t)(tok0 + ra) * 1024 + q * 8;
        pBlo[i] = WTlo + (size_t)(n0 + rb) * 1024 + q * 8;
    }

    f4v acc[4][4];
#pragma unroll
    for (int mi = 0; mi < 4; mi++)
#pragma unroll
        for (int ni = 0; ni < 4; ni++) acc[mi][ni] = (f4v){0.f, 0.f, 0.f, 0.f};

    char* hbase = (char*)sm.hb;
    // prologue: stage k=0 into buffer 0
#pragma unroll
    for (int it = 0; it < 2; it++) {
        gload16(gA[it], hbase + ldst[it]);
        gload16(gB[it], hbase + 16384 + ldst[it]);
    }
    __syncthreads();

    int cur = 0;
    for (int k0 = 0; k0 < 1024; k0 += 32) {
        // stage NEXT k-tile into the other buffer (overlaps with compute)
        if (k0 + 32 < 1024) {
            int nxt = cur ^ 1;
#pragma unroll
            for (int it = 0; it < 2; it++) {
                gload16(gA[it] + k0 + 32, hbase + nxt * 8192 + ldst[it]);
                gload16(gB[it] + k0 + 32, hbase + 16384 + nxt * 8192 + ldst[it]);
            }
        }
        // lo fragments: direct global->reg (single-use, no LDS round-trip)
        s8v alv[4], blv[4], ah[4], bh4[4];
#pragma unroll
        for (int i = 0; i < 4; i++) {
            alv[i] = *(const s8v*)(pAlo[i] + k0);
            blv[i] = *(const s8v*)(pBlo[i] + k0);
        }
        const unsigned short* Abuf = sm.hb + cur * 4096;
        const unsigned short* Bbuf = sm.hb + 8192 + cur * 4096;
#pragma unroll
        for (int i = 0; i < 4; i++) {
            ah[i]  = *(const s8v*)(Abuf + aoff[i]);
            bh4[i] = *(const s8v*)(Bbuf + boff[i]);
        }
        // per-acc order hh -> lh -> hl (bit-identical to previous versions)
#pragma unroll
        for (int mi = 0; mi < 4; mi++)
#pragma unroll
            for (int ni = 0; ni < 4; ni++)
                acc[mi][ni] = __builtin_amdgcn_mfma_f32_16x16x32_bf16(ah[mi], bh4[ni], acc[mi][ni], 0, 0, 0);
#pragma unroll
        for (int mi = 0; mi < 4; mi++)
#pragma unroll
            for (int ni = 0; ni < 4; ni++)
                acc[mi][ni] = __builtin_amdgcn_mfma_f32_16x16x32_bf16(alv[mi], bh4[ni], acc[mi][ni], 0, 0, 0);
#pragma unroll
        for (int mi = 0; mi < 4; mi++)
#pragma unroll
            for (int ni = 0; ni < 4; ni++)
                acc[mi][ni] = __builtin_amdgcn_mfma_f32_16x16x32_bf16(ah[mi], blv[ni], acc[mi][ni], 0, 0, 0);
        __syncthreads();   // drains next-stage loads AND protects buffer reuse
        cur ^= 1;
    }

    // ---- epilogue: per-thread stats from global (no shared preamble) ----
    float mus_r[4][4], iss_r[4][4];
    {
        double zr1 = zrstats[b * 2], zr2 = zrstats[b * 2 + 1];
#pragma unroll
        for (int mi = 0; mi < 4; mi++)
#pragma unroll
            for (int rr = 0; rr < 4; rr++) {
                int m = wm * 64 + mi * 16 + q * 4 + rr;
                size_t tok = (size_t)(tok0 + m);
                double mu = (tokstats[tok * 2] + zr1) * (1.0 / 2048.0);
                double var = (tokstats[tok * 2 + 1] + zr2) * (1.0 / 2048.0) - mu * mu;
                mus_r[mi][rr] = (float)mu;
                iss_r[mi][rr] = (float)(1.0 / sqrt(var + 1e-5));
            }
    }
    float Vn[4], Cn[4], hbn[4];
#pragma unroll
    for (int ni = 0; ni < 4; ni++) {
        int n = wn * 64 + ni * 16 + lr;
        Vn[ni]  = (float)Vmat[(size_t)b * 1024 + n0 + n];
        Cn[ni]  = (float)Cvec[n0 + n];
        hbn[ni] = (float)hbvec[n0 + n];
    }

    float lacc[8];
#pragma unroll
    for (int h = 0; h < 8; h++) lacc[h] = 0.f;
    const int g2 = tid >> 7, mrow = tid & 127;

#pragma unroll
    for (int p2 = 0; p2 < 4; p2++) {
        int jl = wn * 16 + lr;
#pragma unroll
        for (int mi = 0; mi < 4; mi++) {
#pragma unroll
            for (int rr = 0; rr < 4; rr++) {
                int m = wm * 64 + mi * 16 + q * 4 + rr;
                float h = iss_r[mi][rr] * (acc[mi][p2][rr] + Vn[p2] - mus_r[mi][rr] * Cn[p2]) + hbn[p2];
                sm.e.Ht[jl * 133 + m] = geluf(h);
            }
        }
        for (int idx = tid; idx < 512; idx += 256) {
            int j2 = idx >> 4;
            int n = ((j2 >> 4) << 6) + p2 * 16 + (j2 & 15);
            sm.e.W2[idx] = Wr2[(size_t)(n0 + n) * 16 + (idx & 15)];
        }
        __syncthreads();
#pragma unroll 8
        for (int j2 = 0; j2 < 32; j2++) {
            float x = sm.e.Ht[j2 * 133 + mrow];
#pragma unroll
            for (int h = 0; h < 8; h++) lacc[h] += x * sm.e.W2[j2 * 16 + g2 * 8 + h];
        }
        __syncthreads();
    }
#pragma unroll
    for (int h = 0; h < 8; h++)
        atomicAdd(&logits[(size_t)(tok0 + mrow) * 16 + g2 * 8 + h], lacc[h]);
}

// ---------------------------------------------------------------------------
// 9b) legacy router (fp32-A in-loop split) — fallback if workspace too small
//     for the XH/XL precompute.
// ---------------------------------------------------------------------------
__global__ __launch_bounds__(256) void router_kernel(
    const float* __restrict__ X, const unsigned short* __restrict__ WThi,
    const unsigned short* __restrict__ WTlo,
    const double* __restrict__ tokstats, const double* __restrict__ zrstats,
    const double* __restrict__ Vmat, const double* __restrict__ Cvec,
    const double* __restrict__ hbvec, const float* __restrict__ Wr2,
    float* __restrict__ logits)
{
    __shared__ struct {
        union {
            struct { float Af[128 * 32]; unsigned short Bh[128 * 32]; unsigned short Bl[128 * 32]; } g;
            struct { float Ht[64 * 133]; float W2[1024]; } e;
        } u;
        float mus[128], iss[128], Vs[128], Cs[128], hbs[128];
    } sm;

    const int tid = threadIdx.x;
    const int n0 = blockIdx.x * 128, tok0 = blockIdx.y * 128;
    const int b = tok0 >> 12;

    if (tid < 128) {
        int tok = tok0 + tid;
        double mu = (tokstats[(size_t)tok * 2] + zrstats[b * 2]) * (1.0 / 2048.0);
        double var = (tokstats[(size_t)tok * 2 + 1] + zrstats[b * 2 + 1]) * (1.0 / 2048.0) - mu * mu;
        sm.mus[tid] = (float)mu;
        sm.iss[tid] = (float)(1.0 / sqrt(var + 1e-5));
    } else {
        int n = tid - 128;
        sm.Vs[n] = (float)Vmat[(size_t)b * 1024 + n0 + n];
        sm.Cs[n] = (float)Cvec[n0 + n];
        sm.hbs[n] = (float)hbvec[n0 + n];
    }

    const int l = tid & 63, wid = tid >> 6;
    const int wm = wid >> 1, wn = wid & 1;
    const int lr = l & 15, q = l >> 4;

    const float* gA[4]; char* lA[4];
#pragma unroll
    for (int it = 0; it < 4; it++) {
        int c = it * 256 + tid;
        int m = c >> 3;
        int pg = (c & 7) ^ (m & 7);
        gA[it] = X + (size_t)(tok0 + m) * 1024 + pg * 4;
        lA[it] = (char*)sm.u.g.Af + c * 16;
    }
    const unsigned short *gBh[2], *gBl[2];
    char *lBh[2], *lBl[2];
#pragma unroll
    for (int it = 0; it < 2; it++) {
        int c = it * 256 + tid;
        int m = c >> 2;
        int p = (c & 3) ^ ((m >> 1) & 3);
        gBh[it] = WThi + (size_t)(n0 + m) * 1024 + p * 8;
        gBl[it] = WTlo + (size_t)(n0 + m) * 1024 + p * 8;
        lBh[it] = (char*)sm.u.g.Bh + c * 16;
        lBl[it] = (char*)sm.u.g.Bl + c * 16;
    }

    int boff[4], aoffr[4], s7a[4];
#pragma unroll
    for (int i = 0; i < 4; i++) {
        int rb = wn * 64 + i * 16 + lr;
        boff[i] = rb * 32 + ((q ^ ((rb >> 1) & 3)) << 3);
        int ra = wm * 64 + i * 16 + lr;
        aoffr[i] = ra * 32;
        s7a[i] = ra & 7;
    }

    f4v acc[4][4];
#pragma unroll
    for (int mi = 0; mi < 4; mi++)
#pragma unroll
        for (int ni = 0; ni < 4; ni++) acc[mi][ni] = (f4v){0.f, 0.f, 0.f, 0.f};

    for (int k0 = 0; k0 < 1024; k0 += 32) {
#pragma unroll
        for (int it = 0; it < 4; it++) gload16(gA[it] + k0, lA[it]);
#pragma unroll
        for (int it = 0; it < 2; it++) {
            gload16(gBh[it] + k0, lBh[it]);
            gload16(gBl[it] + k0, lBl[it]);
        }
        __syncthreads();

        s8v ah[4], al[4], bh4[4], bl4[4];
#pragma unroll
        for (int i = 0; i < 4; i++) {
            const float* Ab = sm.u.g.Af + aoffr[i];
            float4 f0 = *(const float4*)(Ab + ((((2 * q))     ^ s7a[i]) << 2));
            float4 f1 = *(const float4*)(Ab + ((((2 * q) | 1) ^ s7a[i]) << 2));
            unsigned u0 = __float_as_uint(f0.x), u1 = __float_as_uint(f0.y),
                     u2 = __float_as_uint(f0.z), u3 = __float_as_uint(f0.w),
                     u4 = __float_as_uint(f1.x), u5 = __float_as_uint(f1.y),
                     u6 = __float_as_uint(f1.z), u7 = __float_as_uint(f1.w);
            int4 hi4, lo4;
            hi4.x = (int)((u0 >> 16) | (u1 & 0xffff0000u));
            hi4.y = (int)((u2 >> 16) | (u3 & 0xffff0000u));
            hi4.z = (int)((u4 >> 16) | (u5 & 0xffff0000u));
            hi4.w = (int)((u6 >> 16) | (u7 & 0xffff0000u));
            float r0 = f0.x - __uint_as_float(u0 & 0xffff0000u);
            float r1 = f0.y - __uint_as_float(u1 & 0xffff0000u);
            float r2 = f0.z - __uint_as_float(u2 & 0xffff0000u);
            float r3 = f0.w - __uint_as_float(u3 & 0xffff0000u);
            float r4 = f1.x - __uint_as_float(u4 & 0xffff0000u);
            float r5 = f1.y - __uint_as_float(u5 & 0xffff0000u);
            float r6 = f1.z - __uint_as_float(u6 & 0xffff0000u);
            float r7 = f1.w - __uint_as_float(u7 & 0xffff0000u);
            lo4.x = (int)((__float_as_uint(r0) >> 16) | (__float_as_uint(r1) & 0xffff0000u));
            lo4.y = (int)((__float_as_uint(r2) >> 16) | (__float_as_uint(r3) & 0xffff0000u));
            lo4.z = (int)((__float_as_uint(r4) >> 16) | (__float_as_uint(r5) & 0xffff0000u));
            lo4.w = (int)((__float_as_uint(r6) >> 16) | (__float_as_uint(r7) & 0xffff0000u));
            ah[i] = __builtin_bit_cast(s8v, hi4);
            al[i] = __builtin_bit_cast(s8v, lo4);
            bh4[i] = *(const s8v*)(sm.u.g.Bh + boff[i]);
            bl4[i] = *(const s8v*)(sm.u.g.Bl + boff[i]);
        }
#pragma unroll
        for (int mi = 0; mi < 4; mi++)
#pragma unroll
            for (int ni = 0; ni < 4; ni++) {
                acc[mi][ni] = __builtin_amdgcn_mfma_f32_16x16x32_bf16(ah[mi], bh4[ni], acc[mi][ni], 0, 0, 0);
                acc[mi][ni] = __builtin_amdgcn_mfma_f32_16x16x32_bf16(al[mi], bh4[ni], acc[mi][ni], 0, 0, 0);
                acc[mi][ni] = __builtin_amdgcn_mfma_f32_16x16x32_bf16(ah[mi], bl4[ni], acc[mi][ni], 0, 0, 0);
            }
        __syncthreads();
    }

    float lacc[8];
#pragma unroll
    for (int h = 0; h < 8; h++) lacc[h] = 0.f;
    const int g2 = tid >> 7, mrow = tid & 127;

#pragma unroll
    for (int p = 0; p < 2; p++) {
#pragma unroll
        for (int nh = 0; nh < 2; nh++) {
            int ni = 2 * p + nh;
            int n = wn * 64 + ni * 16 + lr;
            int jl = wn * 32 + nh * 16 + lr;
            float Vnx = sm.Vs[n], Cnx = sm.Cs[n], hbnx = sm.hbs[n];
#pragma unroll
            for (int mi = 0; mi < 4; mi++) {
#pragma unroll
                for (int rr = 0; rr < 4; rr++) {
                    int m = wm * 64 + mi * 16 + q * 4 + rr;
                    float h = sm.iss[m] * (acc[mi][ni][rr] + Vnx - sm.mus[m] * Cnx) + hbnx;
                    sm.u.e.Ht[jl * 133 + m] = geluf(h);
                }
            }
        }
        for (int idx = tid; idx < 1024; idx += 256) {
            int jl = idx >> 4;
            int n = ((jl >> 5) << 6) + p * 32 + (jl & 31);
            sm.u.e.W2[idx] = Wr2[(size_t)(n0 + n) * 16 + (idx & 15)];
        }
        __syncthreads();
#pragma unroll 8
        for (int jl = 0; jl < 64; jl++) {
            float x = sm.u.e.Ht[jl * 133 + mrow];
#pragma unroll
            for (int h = 0; h < 8; h++) lacc[h] += x * sm.u.e.W2[jl * 16 + g2 * 8 + h];
        }
        __syncthreads();
    }
#pragma unroll
    for (int h = 0; h < 8; h++)
        atomicAdd(&logits[(size_t)(tok0 + mrow) * 16 + g2 * 8 + h], lacc[h]);
}

// ---------------------------------------------------------------------------
// 10) softmax + top2 + renorm -> fp32 output; flag tokens with small
//     v(2)-v(3) margin for exact recompute.
// ---------------------------------------------------------------------------
#define FLAG_CAP 16384
__global__ __launch_bounds__(256) void softflag_kernel(
    const float* __restrict__ logits, const float* __restrict__ br2,
    float* __restrict__ out, int* __restrict__ cnt, int* __restrict__ flagged)
{
    int t = blockIdx.x * 256 + threadIdx.x;
    float v[16];
    const float4* lp = (const float4*)(logits + (size_t)t * 16);
    float4 a0 = lp[0], a1 = lp[1], a2 = lp[2], a3 = lp[3];
    v[0] = a0.x; v[1] = a0.y; v[2] = a0.z; v[3] = a0.w;
    v[4] = a1.x; v[5] = a1.y; v[6] = a1.z; v[7] = a1.w;
    v[8] = a2.x; v[9] = a2.y; v[10] = a2.z; v[11] = a2.w;
    v[12] = a3.x; v[13] = a3.y; v[14] = a3.z; v[15] = a3.w;
#pragma unroll
    for (int h = 0; h < 16; h++) v[h] += br2[h];
    int i1 = 0; float b1 = v[0];
#pragma unroll
    for (int h = 1; h < 16; h++) if (v[h] > b1) { b1 = v[h]; i1 = h; }
    int i2 = -1; float b2 = -3.4e38f;
#pragma unroll
    for (int h = 0; h < 16; h++) if (h != i1 && v[h] > b2) { b2 = v[h]; i2 = h; }
    float b3 = -3.4e38f;
#pragma unroll
    for (int h = 0; h < 16; h++) if (h != i1 && h != i2 && v[h] > b3) b3 = v[h];
    float mx = b1;
    float e1 = expf(b1 - mx), e2 = expf(b2 - mx);
    float s = 0.f;
#pragma unroll
    for (int h = 0; h < 16; h++) s += expf(v[h] - mx);
    float a1v = e1 / s, a2v = e2 / s;
    float den = fmaxf(a1v + a2v, 1e-12f);
    float r1 = a1v / den, r2 = a2v / den;
    float o[16];
#pragma unroll
    for (int h = 0; h < 16; h++) o[h] = (h == i1 ? r1 : (h == i2 ? r2 : 0.f));
    float4* op = (float4*)(out + (size_t)t * 16);
    op[0] = make_float4(o[0], o[1], o[2], o[3]);
    op[1] = make_float4(o[4], o[5], o[6], o[7]);
    op[2] = make_float4(o[8], o[9], o[10], o[11]);
    op[3] = make_float4(o[12], o[13], o[14], o[15]);
    if (b2 - b3 < 1e-3f) {
        int slot = atomicAdd(cnt, 1);
        if (slot < FLAG_CAP) flagged[slot] = t;
    }
}

// ---------------------------------------------------------------------------
// 11) per-flagged-token double LN stats
// ---------------------------------------------------------------------------
__global__ void flagstat_kernel(const float* __restrict__ X,
                                const double* __restrict__ zrstats,
                                const int* __restrict__ cnt,
                                const int* __restrict__ flagged,
                                double* __restrict__ fstats)
{
    int n = cnt[0]; if (n > FLAG_CAP) n = FLAG_CAP;
    int s = blockIdx.x;
    if (s >= n) return;
    int tok = flagged[s], b = tok >> 12;
    int l = threadIdx.x;
    double s1 = 0.0, s2 = 0.0;
#pragma unroll
    for (int m = 0; m < 16; m++) {
        double x = (double)X[(size_t)tok * 1024 + l + 64 * m];
        s1 += x; s2 += x * x;
    }
#pragma unroll
    for (int off = 32; off >= 1; off >>= 1) {
        s1 += __shfl_xor(s1, off, 64);
        s2 += __shfl_xor(s2, off, 64);
    }
    if (l == 0) {
        double mu = (s1 + zrstats[b * 2]) * (1.0 / 2048.0);
        double var = (s2 + zrstats[b * 2 + 1]) * (1.0 / 2048.0) - mu * mu;
        fstats[s * 2] = mu;
        fstats[s * 2 + 1] = 1.0 / sqrt(var + 1e-5);
    }
}

// ---------------------------------------------------------------------------
// 12) exact double recompute of logits for flagged tokens — token-parallel.
// ---------------------------------------------------------------------------
__global__ __launch_bounds__(256) void exact2_kernel(
    const float* __restrict__ X, const float* __restrict__ Wr1,
    const float* __restrict__ gr, const double* __restrict__ zv,
    const double* __restrict__ Cvec, const double* __restrict__ hbvec,
    const float* __restrict__ Wr2,
    const int* __restrict__ cnt, const int* __restrict__ flagged,
    const double* __restrict__ fstats, double* __restrict__ exlog)
{
    int n = cnt[0]; if (n > FLAG_CAP) n = FLAG_CAP;
    const int c = blockIdx.y;
    if (c * 16 >= n) return;
    int nt = n - c * 16; if (nt > 16) nt = 16;

    __shared__ double aS[16][65];
    __shared__ double gS[16][129];
    __shared__ double mus[16], iss[16];
    __shared__ int toks[16];

    const int tid = threadIdx.x;
    const int j0 = blockIdx.x * 128;
    const int jl = tid & 127;
    const int j = j0 + jl;
    const int tg = (tid >> 7) * 8;

    if (tid < 16) {
        if (tid < nt) {
            toks[tid] = flagged[c * 16 + tid];
            mus[tid] = fstats[(size_t)(c * 16 + tid) * 2];
            iss[tid] = fstats[(size_t)(c * 16 + tid) * 2 + 1];
        } else {
            toks[tid] = 0; mus[tid] = 0.0; iss[tid] = 0.0;
        }
    }
    __syncthreads();

    double acc[8];
#pragma unroll
    for (int t = 0; t < 8; t++) acc[t] = 0.0;

    for (int i0 = 0; i0 < 2048; i0 += 64) {
        for (int idx = tid; idx < 1024; idx += 256) {
            int t = idx >> 6, ii = idx & 63, i = i0 + ii;
            double v = 0.0;
            if (t < nt) {
                int tok = toks[t];
                if (i < 1024)
                    v = (double)X[(size_t)tok * 1024 + i] * (double)gr[i];
                else
                    v = zv[(size_t)(tok >> 12) * 1024 + (i - 1024)];
            }
            aS[t][ii] = v;
        }
        __syncthreads();
#pragma unroll 8
        for (int ii = 0; ii < 64; ii++) {
            double wv = (double)Wr1[(size_t)(i0 + ii) * 1024 + j];
#pragma unroll
            for (int t = 0; t < 8; t++) acc[t] += aS[tg + t][ii] * wv;
        }
        __syncthreads();
    }

    {
        double Cj = Cvec[j], hbj = hbvec[j];
#pragma unroll
        for (int t = 0; t < 8; t++) {
            double pre = iss[tg + t] * (acc[t] - mus[tg + t] * Cj) + hbj;
            gS[tg + t][jl] = gelud(pre);
        }
    }
    __syncthreads();

    {
        int t = tid >> 4, h = tid & 15;
        double p = 0.0;
#pragma unroll 8
        for (int j2 = 0; j2 < 128; j2++)
            p += gS[t][j2] * (double)Wr2[(size_t)(j0 + j2) * 16 + h];
        if (t < nt)
            atomicAdd(&exlog[(size_t)(c * 16 + t) * 16 + h], p);
    }
}

// ---------------------------------------------------------------------------
// 13) fix kernel: double softmax+top2 for flagged tokens, overwrite out rows
// ---------------------------------------------------------------------------
__global__ __launch_bounds__(256) void fix_kernel(
    const double* __restrict__ exlog, const float* __restrict__ br2,
    const int* __restrict__ cnt, const int* __restrict__ flagged,
    float* __restrict__ out)
{
    int s = blockIdx.x * 256 + threadIdx.x;
    int n = cnt[0]; if (n > FLAG_CAP) n = FLAG_CAP;
    if (s >= n) return;
    int tok = flagged[s];
    double v[16];
#pragma unroll
    for (int h = 0; h < 16; h++) v[h] = exlog[(size_t)s * 16 + h] + (double)br2[h];
    int i1 = 0; double b1 = v[0];
#pragma unroll
    for (int h = 1; h < 16; h++) if (v[h] > b1) { b1 = v[h]; i1 = h; }
    int i2 = -1; double b2 = -1e300;
#pragma unroll
    for (int h = 0; h < 16; h++) if (h != i1 && v[h] > b2) { b2 = v[h]; i2 = h; }
    double ssum = 0.0;
#pragma unroll
    for (int h = 0; h < 16; h++) ssum += exp(v[h] - b1);
    double a1v = exp(b1 - b1) / ssum, a2v = exp(b2 - b1) / ssum;
    double den = a1v + a2v; if (den < 1e-12) den = 1e-12;
    float r1 = (float)(a1v / den), r2 = (float)(a2v / den);
#pragma unroll
    for (int h = 0; h < 16; h++)
        out[(size_t)tok * 16 + h] = (h == i1 ? r1 : (h == i2 ? r2 : 0.f));
}

// ---------------------------------------------------------------------------
// launch
// ---------------------------------------------------------------------------
extern "C" void kernel_launch(void* const* d_in, const int* in_sizes, int n_in,
                              void* d_out, int out_size, void* d_ws, size_t ws_size,
                              hipStream_t stream)
{
    const float* X      = (const float*)d_in[0];
    const float* z_in   = (const float*)d_in[1];
    const int*   stepi  = (const int*)d_in[2];
    const float* g_pool = (const float*)d_in[3];
    const float* b_pool = (const float*)d_in[4];
    const float* W_inp  = (const float*)d_in[5];
    const float* b_inp  = (const float*)d_in[6];
    const float* Wt1    = (const float*)d_in[7];
    const float* bt1    = (const float*)d_in[8];
    const float* Wt2    = (const float*)d_in[9];
    const float* bt2    = (const float*)d_in[10];
    const float* Wc1    = (const float*)d_in[11];
    const float* bc1    = (const float*)d_in[12];
    const float* Wc2    = (const float*)d_in[13];
    const float* bc2    = (const float*)d_in[14];
    const float* W_mod  = (const float*)d_in[15];
    const float* b_mod  = (const float*)d_in[16];
    const float* Wm1    = (const float*)d_in[17];
    const float* bm1    = (const float*)d_in[18];
    const float* Wm2    = (const float*)d_in[19];
    const float* bm2    = (const float*)d_in[20];
    const float* Wf     = (const float*)d_in[21];
    const float* bf_b   = (const float*)d_in[22];
    const float* gz     = (const float*)d_in[23];
    const float* bz     = (const float*)d_in[24];
    const float* gr     = (const float*)d_in[25];
    const float* br     = (const float*)d_in[26];
    const float* Wr1    = (const float*)d_in[27];
    const float* br1    = (const float*)d_in[28];
    const float* Wr2    = (const float*)d_in[29];
    const float* br2    = (const float*)d_in[30];

    char* wsb = (char*)d_ws;
    // ---- workspace layout (byte offsets) ----
    const size_t OB_LOGA  = 0;         // float[524288]      2,097,152
    const size_t OB_EXLOG = 2097152;   // double[16384*16]   2,097,152
    const size_t OB_CNT   = 4194304;   // int[16]            64
    const size_t OB_FLAG  = 4194368;   // int[16384]         65,536
    const size_t OB_MACC  = 4259904;   // double[8192]       65,536
    const size_t OB_XCTRL = 4325440;   // double[8192]
    const size_t OB_TH1   = 4390976;   // double[4096]
    const size_t OB_TEMB  = 4423744;   // double[1024]
    const size_t OB_CH    = 4431936;   // double[8192]
    const size_t OB_COND  = 4497472;   // double[8192]
    const size_t OB_MOD   = 4563008;   // double[2*32768]
    const size_t OB_H1    = 5087296;   // double[2*32768]
    const size_t OB_H2    = 5611584;   // double[2*8192]
    const size_t OB_ZFPRE = 5742656;   // double[8192]
    const size_t OB_V     = 5808192;   // double[8192]
    const size_t OB_TOKST = 5873728;   // double[65536]
    const size_t OB_FSTAT = 6398016;   // double[32768]
    const size_t OB_EMB   = 6660160;   // double[1024]
    const size_t OB_ZB0   = 6668352;   // double[8192]
    const size_t OB_ZB1   = 6733888;   // double[8192]
    const size_t OB_ZST   = 6799424;   // double[16]
    const size_t OB_ZRST  = 6799552;   // double[16]
    const size_t OB_ZV    = 6799680;   // double[8192]
    const size_t OB_CVEC  = 6865216;   // double[1024]   (zeroed: colsum atomics)
    const size_t OB_HB    = 6873408;   // double[1024]   (zeroed: colsum atomics)
    const size_t ZEND     = 6881600;   // end of zeroed region
    const size_t OB_WTHI  = 6881600;   // ushort[1M]         2,097,152
    const size_t OB_WTLO  = 8978752;   // ushort[1M]         2,097,152
    const size_t OB_XH    = 11075904;  // ushort[32768*1024] 67,108,864
    const size_t OB_XL    = 78184768;  // ushort[32768*1024] 67,108,864
    const size_t WS_BIG   = 145293632; // required for bf16-A fast path

    unsigned short* WThi = (unsigned short*)(wsb + OB_WTHI);
    unsigned short* WTlo = (unsigned short*)(wsb + OB_WTLO);
    int* cntp  = (int*)(wsb + OB_CNT);
    int* flagp = (int*)(wsb + OB_FLAG);

    const bool big = ws_size >= WS_BIG;
    unsigned short* XHp = big ? (unsigned short*)(wsb + OB_XH) : nullptr;
    unsigned short* XLp = big ? (unsigned short*)(wsb + OB_XL) : nullptr;

    hipMemsetAsync(d_ws, 0, ZEND, stream);

    pool_kernel<<<dim3(64, 8), 256, 0, stream>>>(X, (double*)(wsb + OB_MACC),
                                                 (double*)(wsb + OB_TOKST), XHp, XLp);
    prep_kernel<<<1, 256, 0, stream>>>(stepi, z_in, (double*)(wsb + OB_EMB), (double*)(wsb + OB_ZB0));
    prepw_kernel<<<dim3(16, 16), 256, 0, stream>>>(Wr1, gr, WThi, WTlo);
    colsum_kernel<<<dim3(4, 16), 256, 0, stream>>>(Wr1, gr, br, br1,
        (double*)(wsb + OB_CVEC), (double*)(wsb + OB_HB));

    // x_ctrl_pre = g @ W_inp
    gemvd_kernel<1, 8><<<dim3(4, 16), 256, 0, stream>>>(W_inp, 1024, 1024, 64, 1024,
        (double*)(wsb + OB_MACC), nullptr, nullptr, g_pool, b_pool, (double*)(wsb + OB_XCTRL));
    // th1_pre = emb @ Wt1
    gemvd_kernel<0, 1><<<dim3(16, 16), 256, 0, stream>>>(Wt1, 1024, 4096, 64, 1024,
        (double*)(wsb + OB_EMB), nullptr, nullptr, nullptr, nullptr, (double*)(wsb + OB_TH1));
    // t_embed_pre = gelu(th1_pre + bt1) @ Wt2
    gemvd_kernel<2, 1><<<dim3(4, 16), 256, 0, stream>>>(Wt2, 4096, 1024, 256, 4096,
        (double*)(wsb + OB_TH1), nullptr, nullptr, bt1, nullptr, (double*)(wsb + OB_TEMB));
    // ch_pre = concat(x_ctrl_pre+b_inp, t_embed_pre+bt2) @ Wc1
    gemvd_kernel<4, 8><<<dim3(4, 16), 256, 0, stream>>>(Wc1, 2048, 1024, 128, 1024,
        (double*)(wsb + OB_XCTRL), (double*)(wsb + OB_TEMB), nullptr, b_inp, bt2, (double*)(wsb + OB_CH));
    // cond_pre = gelu(ch_pre + bc1) @ Wc2
    gemvd_kernel<2, 8><<<dim3(4, 16), 256, 0, stream>>>(Wc2, 1024, 1024, 64, 1024,
        (double*)(wsb + OB_CH), nullptr, nullptr, bc1, nullptr, (double*)(wsb + OB_COND));

    stats8_kernel<<<8, 256, 0, stream>>>((double*)(wsb + OB_ZB0), (double*)(wsb + OB_ZST));

    for (int ll = 0; ll < 2; ll++) {
        double* zcur  = (double*)(wsb + (ll == 0 ? OB_ZB0 : OB_ZB1));
        double* znext = (double*)(wsb + (ll == 0 ? OB_ZB1 : OB_ZB0));
        double* modp  = (double*)(wsb + OB_MOD) + (size_t)ll * 32768;
        double* h1p   = (double*)(wsb + OB_H1) + (size_t)ll * 32768;
        double* h2p   = (double*)(wsb + OB_H2) + (size_t)ll * 8192;
        gemvd_kernel<2, 8><<<dim3(16, 16), 256, 0, stream>>>(W_mod + (size_t)ll * 4194304,
            1024, 4096, 64, 1024, (double*)(wsb + OB_COND), nullptr, nullptr, bc2, nullptr, modp);
        gemvd_kernel<3, 8><<<dim3(16, 16), 256, 0, stream>>>(Wm1 + (size_t)ll * 4194304,
            1024, 4096, 64, 1024, zcur, (double*)(wsb + OB_ZST), modp, b_mod + ll * 4096, nullptr, h1p);
        gemvd_kernel<2, 8><<<dim3(4, 16), 256, 0, stream>>>(Wm2 + (size_t)ll * 4194304,
            4096, 1024, 256, 4096, h1p, nullptr, nullptr, bm1 + ll * 4096, nullptr, h2p);
        resid_kernel<<<8, 256, 0, stream>>>(zcur, h2p, bm2 + ll * 1024, modp,
                                            b_mod + ll * 4096, znext, (double*)(wsb + OB_ZST));
    }

    // zf_pre = z @ Wf
    gemvd_kernel<0, 8><<<dim3(4, 16), 256, 0, stream>>>(Wf, 1024, 1024, 64, 1024,
        (double*)(wsb + OB_ZB0), nullptr, nullptr, nullptr, nullptr, (double*)(wsb + OB_ZFPRE));
    zfinal_kernel<<<8, 256, 0, stream>>>((double*)(wsb + OB_ZFPRE), bf_b, gz, bz, gr,
                                         (double*)(wsb + OB_ZV), (double*)(wsb + OB_ZRST));
    // V = zv @ Wr1[1024:,:]
    gemvd_kernel<0, 8><<<dim3(4, 16), 256, 0, stream>>>(Wr1 + (size_t)1024 * 1024,
        1024, 1024, 64, 1024, (double*)(wsb + OB_ZV), nullptr, nullptr, nullptr, nullptr,
        (double*)(wsb + OB_V));

    if (big) {
        router3_kernel<<<2048, 256, 0, stream>>>(XHp, XLp, WThi, WTlo,
            (double*)(wsb + OB_TOKST), (double*)(wsb + OB_ZRST), (double*)(wsb + OB_V),
            (double*)(wsb + OB_CVEC), (double*)(wsb + OB_HB), Wr2, (float*)(wsb + OB_LOGA));
    } else {
        router_kernel<<<dim3(8, 256), 256, 0, stream>>>(X, WThi, WTlo,
            (double*)(wsb + OB_TOKST), (double*)(wsb + OB_ZRST), (double*)(wsb + OB_V),
            (double*)(wsb + OB_CVEC), (double*)(wsb + OB_HB), Wr2, (float*)(wsb + OB_LOGA));
    }

    softflag_kernel<<<128, 256, 0, stream>>>((float*)(wsb + OB_LOGA), br2,
        (float*)d_out, cntp, flagp);
    flagstat_kernel<<<16384, 64, 0, stream>>>(X, (double*)(wsb + OB_ZRST), cntp, flagp,
        (double*)(wsb + OB_FSTAT));
    exact2_kernel<<<dim3(8, 1024), 256, 0, stream>>>(X, Wr1, gr, (double*)(wsb + OB_ZV),
        (double*)(wsb + OB_CVEC), (double*)(wsb + OB_HB), Wr2, cntp, flagp,
        (double*)(wsb + OB_FSTAT), (double*)(wsb + OB_EXLOG));
    fix_kernel<<<64, 256, 0, stream>>>((double*)(wsb + OB_EXLOG), br2, cntp, flagp,
        (float*)d_out);
}

// Round 4
// 1626.151 us; speedup vs baseline: 1.0809x; 1.0809x over previous
//
#include <hip/hip_runtime.h>
#include <cstdint>
#include <cstddef>
#include <math.h>

#define DEV __device__ __forceinline__

// ---------- constants ----------
// B=8, S=4096, D=1024, DC=1024, H=16, L=2, TOPK=2, MAX_DEPTH=32, EPS=1e-5
// ALL array inputs are FP32 (reference uses jnp.float32 throughout). Output FP32.

typedef short s8v __attribute__((ext_vector_type(8)));   // 8 bf16 (4 VGPRs)
typedef float f4v __attribute__((ext_vector_type(4)));   // MFMA acc

DEV float geluf(float x) { return 0.5f * x * (1.0f + erff(x * 0.70710678118654752440f)); }
DEV double gelud(double x) { return 0.5 * x * (1.0 + erf(x * 0.70710678118654752440)); }
DEV unsigned short f2us(float f) {          // fp32 -> bf16 RNE
    unsigned u = __float_as_uint(f);
    u += 0x7fffu + ((u >> 16) & 1u);
    return (unsigned short)(u >> 16);
}

DEV void gload16(const void* g, void* l) {
    __builtin_amdgcn_global_load_lds(
        (const __attribute__((address_space(1))) void*)g,
        (__attribute__((address_space(3))) void*)l, 16, 0, 0);
}

DEV void blockReduce2d(double& a, double& b, double* lds /*>=8 doubles*/) {
    __syncthreads();
#pragma unroll
    for (int off = 32; off >= 1; off >>= 1) {
        a += __shfl_xor(a, off, 64);
        b += __shfl_xor(b, off, 64);
    }
    int w = threadIdx.x >> 6;
    if ((threadIdx.x & 63) == 0) { lds[w] = a; lds[4 + w] = b; }
    __syncthreads();
    a = lds[0] + lds[1] + lds[2] + lds[3];
    b = lds[4] + lds[5] + lds[6] + lds[7];
    __syncthreads();
}

// ---------------------------------------------------------------------------
// 1) pool pass: per-token LN stats over D=1024 (double); accumulate
//    sum_s (x-mu)*istd per (b,d) into Macc (double atomics); store per-token
//    (sumX, sumX^2) double pairs. Also (if XH/XL non-null) emit the bf16
//    truncation hi/lo split of X for the bf16-A router.
// ---------------------------------------------------------------------------
__global__ __launch_bounds__(256) void pool_kernel(
    const float* __restrict__ X, double* __restrict__ Macc,
    double* __restrict__ tokstats,
    unsigned short* __restrict__ XH, unsigned short* __restrict__ XL)
{
    int b = blockIdx.y;
    int w = threadIdx.x >> 6, l = threadIdx.x & 63;
    int s0 = blockIdx.x * 64 + w * 16;
    double acc[16];
#pragma unroll
    for (int e = 0; e < 16; e++) acc[e] = 0.0;
    __shared__ double red[4][1024];

    for (int t = 0; t < 16; t++) {
        int s = s0 + t;
        const float* row = X + (size_t)(b * 4096 + s) * 1024;
        float xv[16];
#pragma unroll
        for (int m = 0; m < 16; m++) xv[m] = row[l + 64 * m];
        if (XH) {
            size_t base = (size_t)(b * 4096 + s) * 1024 + l;
#pragma unroll
            for (int m = 0; m < 16; m++) {
                unsigned u = __float_as_uint(xv[m]);
                XH[base + 64 * m] = (unsigned short)(u >> 16);
                float r = xv[m] - __uint_as_float(u & 0xffff0000u);
                XL[base + 64 * m] = (unsigned short)(__float_as_uint(r) >> 16);
            }
        }
        double s1 = 0.0, s2 = 0.0;
#pragma unroll
        for (int m = 0; m < 16; m++) { double x = (double)xv[m]; s1 += x; s2 += x * x; }
#pragma unroll
        for (int off = 32; off >= 1; off >>= 1) {
            s1 += __shfl_xor(s1, off, 64);
            s2 += __shfl_xor(s2, off, 64);
        }
        double mu = s1 * (1.0 / 1024.0);
        double var = s2 * (1.0 / 1024.0) - mu * mu;
        double istd = 1.0 / sqrt(var + 1e-5);
        if (l == 0) {
            tokstats[(size_t)(b * 4096 + s) * 2]     = s1;
            tokstats[(size_t)(b * 4096 + s) * 2 + 1] = s2;
        }
#pragma unroll
        for (int m = 0; m < 16; m++) acc[m] += ((double)xv[m] - mu) * istd;
    }
#pragma unroll
    for (int m = 0; m < 16; m++) red[w][l + 64 * m] = acc[m];
    __syncthreads();
    for (int d = threadIdx.x; d < 1024; d += 256)
        atomicAdd(&Macc[b * 1024 + d], red[0][d] + red[1][d] + red[2][d] + red[3][d]);
}

// ---------------------------------------------------------------------------
// 2) prep: sigma schedule + sinusoidal embedding (double), z -> double
// ---------------------------------------------------------------------------
__global__ void prep_kernel(const int* __restrict__ step_idx,
                            const float* __restrict__ z,
                            double* __restrict__ emb, double* __restrict__ z0)
{
    int step = step_idx[0];
    if (step > 31) step = 31;
    double t = (double)step / 31.0;
    double sig = cos(t * 1.5707963267948966);
    if (sig < 1e-4) sig = 1e-4;
    for (int k = threadIdx.x; k < 512; k += 256) {
        double fr = exp(-9.210340371976184 * ((double)k / 512.0));
        double a = sig * fr;
        emb[k] = cos(a);
        emb[512 + k] = sin(a);
    }
    for (int i = threadIdx.x; i < 8192; i += 256) z0[i] = (double)z[i];
}

// ---------------------------------------------------------------------------
// 3) prepw: WThi/WTlo[j][i] = bf16 hi/lo split of gr[i]*Wr1[i][j], i<1024,
//    transposed for MFMA B-operand.
// ---------------------------------------------------------------------------
__global__ __launch_bounds__(256) void prepw_kernel(
    const float* __restrict__ Wr1, const float* __restrict__ gr,
    unsigned short* __restrict__ WThi, unsigned short* __restrict__ WTlo)
{
    __shared__ unsigned short th[64][65], tl[64][65];
    int tx = threadIdx.x & 63, ty = threadIdx.x >> 6;
    int i0 = blockIdx.y * 64, j0 = blockIdx.x * 64;
#pragma unroll 4
    for (int k = 0; k < 16; k++) {
        int row = ty * 16 + k;
        float w = (float)((double)gr[i0 + row] * (double)Wr1[(size_t)(i0 + row) * 1024 + j0 + tx]);
        unsigned short hi = f2us(w);
        float hif = __uint_as_float((unsigned)hi << 16);
        unsigned short lo = f2us(w - hif);
        th[row][tx] = hi;
        tl[row][tx] = lo;
    }
    __syncthreads();
#pragma unroll 4
    for (int k = 0; k < 16; k++) {
        int row = ty * 16 + k;
        WThi[(size_t)(j0 + row) * 1024 + i0 + tx] = th[tx][row];
        WTlo[(size_t)(j0 + row) * 1024 + i0 + tx] = tl[tx][row];
    }
}

// ---------------------------------------------------------------------------
// 4) column sums over all 2048 rows (double, k-split + atomics):
//    C[j] = sum gr_i*W_ij ; hb[j] = sum br_i*W_ij + br1[j]
// ---------------------------------------------------------------------------
__global__ __launch_bounds__(256) void colsum_kernel(
    const float* __restrict__ Wr1, const float* __restrict__ gr,
    const float* __restrict__ br, const float* __restrict__ br1,
    double* __restrict__ Cvec, double* __restrict__ hbvec)
{
    int j = blockIdx.x * 256 + threadIdx.x;
    int i0 = blockIdx.y * 128;
    double c = 0.0, bw = 0.0;
#pragma unroll 4
    for (int k = 0; k < 128; k++) {
        int i = i0 + k;
        double wv = (double)Wr1[(size_t)i * 1024 + j];
        c += (double)gr[i] * wv;
        bw += (double)br[i] * wv;
    }
    if (blockIdx.y == 0) bw += (double)br1[j];
    atomicAdd(&Cvec[j], c);
    atomicAdd(&hbvec[j], bw);
}

// ---------------------------------------------------------------------------
// 5) generic small-M GEMM (double accumulation), K-split over grid.y with
//    double atomicAdd outputs. IN modes fold the previous op's epilogue.
// ---------------------------------------------------------------------------
template <int IN, int R>
__global__ __launch_bounds__(256) void gemvd_kernel(
    const float* __restrict__ W, int K, int N, int kchunk, int kstr,
    const double* __restrict__ in0, const double* __restrict__ in1,
    const double* __restrict__ in2,
    const float* __restrict__ ba0, const float* __restrict__ ba1,
    double* __restrict__ out)
{
    const int CH = 64;
    __shared__ double xin[R][CH];
    int tid = threadIdx.x;
    int j = blockIdx.x * 256 + tid;
    int kbeg = blockIdx.y * kchunk;
    double acc[R];
#pragma unroll
    for (int r = 0; r < R; r++) acc[r] = 0.0;

    for (int k0 = kbeg; k0 < kbeg + kchunk; k0 += CH) {
        for (int idx = tid; idx < R * CH; idx += 256) {
            int r = idx / CH, ii = idx % CH, i = k0 + ii;
            double v;
            if (IN == 0) {
                v = in0[(size_t)r * kstr + i] + (ba0 ? (double)ba0[i] : 0.0);
            } else if (IN == 1) {            // pooled-mean -> g (affine LN params)
                v = (double)ba0[i] * (in0[(size_t)r * kstr + i] * (1.0 / 4096.0)) + (double)ba1[i];
            } else if (IN == 2) {            // gelu(prev + bias)
                v = gelud(in0[(size_t)r * kstr + i] + (ba0 ? (double)ba0[i] : 0.0));
            } else if (IN == 3) {            // adaLN: ln(z)*(1+s1)+sh1
                double mu = in1[r * 2], istd = in1[r * 2 + 1];
                double s1 = in2[(size_t)r * 4096 + i] + (double)ba0[i];
                double sh1 = in2[(size_t)r * 4096 + 1024 + i] + (double)ba0[1024 + i];
                v = (in0[(size_t)r * 1024 + i] - mu) * istd * (1.0 + s1) + sh1;
            } else {                         // IN==4: concat(x_ctrl+b_inp, t_embed+bt2)
                v = (i < 1024) ? (in0[(size_t)r * 1024 + i] + (double)ba0[i])
                               : (in1[i - 1024] + (double)ba1[i - 1024]);
            }
            xin[r][ii] = v;
        }
        __syncthreads();
#pragma unroll 16
        for (int kk = 0; kk < CH; kk++) {
            double wv = (double)W[(size_t)(k0 + kk) * N + j];
#pragma unroll
            for (int r = 0; r < R; r++) acc[r] += xin[r][kk] * wv;
        }
        __syncthreads();
    }
#pragma unroll
    for (int r = 0; r < R; r++) atomicAdd(&out[(size_t)r * N + j], acc[r]);
}

// ---------------------------------------------------------------------------
// 6) per-row (8) stats: mu, istd (double)
// ---------------------------------------------------------------------------
__global__ void stats8_kernel(const double* __restrict__ z, double* __restrict__ zstats)
{
    __shared__ double lds[8];
    int r = blockIdx.x, tid = threadIdx.x;
    double s = 0.0, ss = 0.0;
    for (int i = tid; i < 1024; i += 256) {
        double v = z[(size_t)r * 1024 + i];
        s += v; ss += v * v;
    }
    blockReduce2d(s, ss, lds);
    if (tid == 0) {
        double mu = s * (1.0 / 1024.0);
        double var = ss * (1.0 / 1024.0) - mu * mu;
        zstats[r * 2] = mu;
        zstats[r * 2 + 1] = 1.0 / sqrt(var + 1e-5);
    }
}

// ---------------------------------------------------------------------------
// 7) residual epilogue of a denoise block + stats of new z (double)
// ---------------------------------------------------------------------------
__global__ void resid_kernel(const double* __restrict__ zc, const double* __restrict__ h2pre,
                             const float* __restrict__ bm2,
                             const double* __restrict__ modpre,
                             const float* __restrict__ bmod,
                             double* __restrict__ znew, double* __restrict__ zstats)
{
    __shared__ double lds[8];
    int r = blockIdx.x, tid = threadIdx.x;
    double s = 0.0, ss = 0.0;
#pragma unroll
    for (int c = 0; c < 4; c++) {
        int i = tid + c * 256;
        double s2 = modpre[(size_t)r * 4096 + 2048 + i] + (double)bmod[2048 + i];
        double sh2 = modpre[(size_t)r * 4096 + 3072 + i] + (double)bmod[3072 + i];
        double h = h2pre[(size_t)r * 1024 + i] + (double)bm2[i];
        double v = zc[(size_t)r * 1024 + i] + h * (1.0 + s2) + sh2;
        znew[(size_t)r * 1024 + i] = v;
        s += v; ss += v * v;
    }
    blockReduce2d(s, ss, lds);
    if (tid == 0) {
        double mu = s * (1.0 / 1024.0);
        double var = ss * (1.0 / 1024.0) - mu * mu;
        zstats[r * 2] = mu;
        zstats[r * 2 + 1] = 1.0 / sqrt(var + 1e-5);
    }
}

// ---------------------------------------------------------------------------
// 8) final z LN (gz,bz affine) -> zv (= z_final*gr_z) + router z-part sums
// ---------------------------------------------------------------------------
__global__ void zfinal_kernel(const double* __restrict__ zfpre,
                              const float* __restrict__ bfb,
                              const float* __restrict__ gz,
                              const float* __restrict__ bz,
                              const float* __restrict__ gr,
                              double* __restrict__ zv, double* __restrict__ zrstats)
{
    __shared__ double xb[1024];
    __shared__ double lds[8];
    int r = blockIdx.x, tid = threadIdx.x;
    double s = 0.0, ss = 0.0;
#pragma unroll
    for (int c = 0; c < 4; c++) {
        int i = tid + c * 256;
        double x = zfpre[(size_t)r * 1024 + i] + (double)bfb[i];
        xb[i] = x;
        s += x; ss += x * x;
    }
    blockReduce2d(s, ss, lds);
    double mu = s * (1.0 / 1024.0);
    double var = ss * (1.0 / 1024.0) - mu * mu;
    double istd = 1.0 / sqrt(var + 1e-5);
    double s2 = 0.0, s2s = 0.0;
#pragma unroll
    for (int c = 0; c < 4; c++) {
        int i = tid + c * 256;
        double zf = (xb[i] - mu) * istd * (double)gz[i] + (double)bz[i];
        zv[(size_t)r * 1024 + i] = zf * (double)gr[1024 + i];
        s2 += zf; s2s += zf * zf;
    }
    blockReduce2d(s2, s2s, lds);
    if (tid == 0) { zrstats[r * 2] = s2; zrstats[r * 2 + 1] = s2s; }
}

// ---------------------------------------------------------------------------
// 9a) router stage A v4: G = X @ (gr.Wr1_x)^T, 3-term bf16 MFMA.
//     ALL FOUR streams (Ah,Al,Bh,Bl) staged via coalesced global_load_lds
//     (pre-swizzled source), 2-phase double buffer (64KB LDS), ONE barrier
//     per k-step. Conflict-free XOR-swizzled ds_read_b128 (r3-proven).
//     NO scattered per-lane global loads (r3's L2-transaction bottleneck).
//     XCD-chunked 1D grid; 4-pass 32-column epilogue.
// ---------------------------------------------------------------------------
__global__ __launch_bounds__(256) void router4_kernel(
    const unsigned short* __restrict__ XH, const unsigned short* __restrict__ XL,
    const unsigned short* __restrict__ WThi, const unsigned short* __restrict__ WTlo,
    const double* __restrict__ tokstats, const double* __restrict__ zrstats,
    const double* __restrict__ Vmat, const double* __restrict__ Cvec,
    const double* __restrict__ hbvec, const float* __restrict__ Wr2,
    float* __restrict__ logits)
{
    __shared__ union {
        unsigned short hb[32768];                         // 2 bufs x 4 streams x 4096 (64KB)
        struct { float Ht[32 * 133]; float W2[512]; } e;  // 19KB epilogue
    } sm;

    const int tid = threadIdx.x;
    // XCD-chunked mapping: 2048 blocks, 8 n-tiles of one token tile adjacent
    // on the same XCD.
    const int id = blockIdx.x;
    const int xcd = id & 7, local = id >> 3;
    const int tokTile = xcd * 32 + (local >> 3);
    const int nTile = local & 7;
    const int n0 = nTile * 128, tok0 = tokTile * 128;
    const int b = tok0 >> 12;

    const int l = tid & 63, wid = tid >> 6;
    const int wm = wid >> 1, wn = wid & 1;
    const int lr = l & 15, q = l >> 4;

    // staging: 8 gload16 per thread per k-step (4 streams x 2 chunks).
    // stream order in LDS: [Ah | Al | Bh | Bl], 4096 ushorts (8KB) each.
    const unsigned short* gS[8]; int ldst[8];
    {
        const unsigned short* srcs[4] = {
            XH + (size_t)tok0 * 1024, XL + (size_t)tok0 * 1024,
            WThi + (size_t)n0 * 1024, WTlo + (size_t)n0 * 1024 };
#pragma unroll
        for (int s = 0; s < 4; s++)
#pragma unroll
            for (int it = 0; it < 2; it++) {
                int c = it * 256 + tid;
                int m = c >> 2, p = (c & 3) ^ ((m >> 1) & 3);
                gS[s * 2 + it] = srcs[s] + (size_t)m * 1024 + p * 8;
                ldst[s * 2 + it] = s * 8192 + c * 16;   // bytes within one buffer
            }
    }

    int aoff[4], boff[4];
#pragma unroll
    for (int i = 0; i < 4; i++) {
        int ra = wm * 64 + i * 16 + lr;
        aoff[i] = ra * 32 + ((q ^ ((ra >> 1) & 3)) << 3);
        int rb = wn * 64 + i * 16 + lr;
        boff[i] = rb * 32 + ((q ^ ((rb >> 1) & 3)) << 3);
    }

    f4v acc[4][4];
#pragma unroll
    for (int mi = 0; mi < 4; mi++)
#pragma unroll
        for (int ni = 0; ni < 4; ni++) acc[mi][ni] = (f4v){0.f, 0.f, 0.f, 0.f};

    char* hbase = (char*)sm.hb;
    // prologue: stage k=0 into buffer 0
#pragma unroll
    for (int t = 0; t < 8; t++) gload16(gS[t], hbase + ldst[t]);
    __syncthreads();

    int cur = 0;
    for (int k0 = 0; k0 < 1024; k0 += 32) {
        // stage NEXT k-tile into the other buffer (issues before compute)
        if (k0 + 32 < 1024) {
            int nxt = cur ^ 1;
#pragma unroll
            for (int t = 0; t < 8; t++)
                gload16(gS[t] + k0 + 32, hbase + nxt * 32768 + ldst[t]);
        }
        const unsigned short* base = sm.hb + cur * 16384;  // ushort units
        s8v ah[4], alv[4], bh4[4], blv[4];
#pragma unroll
        for (int i = 0; i < 4; i++) {
            ah[i]  = *(const s8v*)(base + aoff[i]);
            alv[i] = *(const s8v*)(base + 4096 + aoff[i]);
            bh4[i] = *(const s8v*)(base + 8192 + boff[i]);
            blv[i] = *(const s8v*)(base + 12288 + boff[i]);
        }
        // per-acc order hh -> lh -> hl (bit-identical to previous versions)
#pragma unroll
        for (int mi = 0; mi < 4; mi++)
#pragma unroll
            for (int ni = 0; ni < 4; ni++)
                acc[mi][ni] = __builtin_amdgcn_mfma_f32_16x16x32_bf16(ah[mi], bh4[ni], acc[mi][ni], 0, 0, 0);
#pragma unroll
        for (int mi = 0; mi < 4; mi++)
#pragma unroll
            for (int ni = 0; ni < 4; ni++)
                acc[mi][ni] = __builtin_amdgcn_mfma_f32_16x16x32_bf16(alv[mi], bh4[ni], acc[mi][ni], 0, 0, 0);
#pragma unroll
        for (int mi = 0; mi < 4; mi++)
#pragma unroll
            for (int ni = 0; ni < 4; ni++)
                acc[mi][ni] = __builtin_amdgcn_mfma_f32_16x16x32_bf16(ah[mi], blv[ni], acc[mi][ni], 0, 0, 0);
        __syncthreads();   // drains next-stage loads AND protects buffer reuse
        cur ^= 1;
    }

    // ---- epilogue: per-thread stats from global (no shared preamble) ----
    float mus_r[4][4], iss_r[4][4];
    {
        double zr1 = zrstats[b * 2], zr2 = zrstats[b * 2 + 1];
#pragma unroll
        for (int mi = 0; mi < 4; mi++)
#pragma unroll
            for (int rr = 0; rr < 4; rr++) {
                int m = wm * 64 + mi * 16 + q * 4 + rr;
                size_t tok = (size_t)(tok0 + m);
                double mu = (tokstats[tok * 2] + zr1) * (1.0 / 2048.0);
                double var = (tokstats[tok * 2 + 1] + zr2) * (1.0 / 2048.0) - mu * mu;
                mus_r[mi][rr] = (float)mu;
                iss_r[mi][rr] = (float)(1.0 / sqrt(var + 1e-5));
            }
    }
    float Vn[4], Cn[4], hbn[4];
#pragma unroll
    for (int ni = 0; ni < 4; ni++) {
        int n = wn * 64 + ni * 16 + lr;
        Vn[ni]  = (float)Vmat[(size_t)b * 1024 + n0 + n];
        Cn[ni]  = (float)Cvec[n0 + n];
        hbn[ni] = (float)hbvec[n0 + n];
    }

    float lacc[8];
#pragma unroll
    for (int h = 0; h < 8; h++) lacc[h] = 0.f;
    const int g2 = tid >> 7, mrow = tid & 127;

#pragma unroll
    for (int p2 = 0; p2 < 4; p2++) {
        int jl = wn * 16 + lr;
#pragma unroll
        for (int mi = 0; mi < 4; mi++) {
#pragma unroll
            for (int rr = 0; rr < 4; rr++) {
                int m = wm * 64 + mi * 16 + q * 4 + rr;
                float h = iss_r[mi][rr] * (acc[mi][p2][rr] + Vn[p2] - mus_r[mi][rr] * Cn[p2]) + hbn[p2];
                sm.e.Ht[jl * 133 + m] = geluf(h);
            }
        }
        for (int idx = tid; idx < 512; idx += 256) {
            int j2 = idx >> 4;
            int n = ((j2 >> 4) << 6) + p2 * 16 + (j2 & 15);
            sm.e.W2[idx] = Wr2[(size_t)(n0 + n) * 16 + (idx & 15)];
        }
        __syncthreads();
#pragma unroll 8
        for (int j2 = 0; j2 < 32; j2++) {
            float x = sm.e.Ht[j2 * 133 + mrow];
#pragma unroll
            for (int h = 0; h < 8; h++) lacc[h] += x * sm.e.W2[j2 * 16 + g2 * 8 + h];
        }
        __syncthreads();
    }
#pragma unroll
    for (int h = 0; h < 8; h++)
        atomicAdd(&logits[(size_t)(tok0 + mrow) * 16 + g2 * 8 + h], lacc[h]);
}

// ---------------------------------------------------------------------------
// 9b) legacy router (fp32-A in-loop split) — fallback if workspace too small
//     for the XH/XL precompute.
// ---------------------------------------------------------------------------
__global__ __launch_bounds__(256) void router_kernel(
    const float* __restrict__ X, const unsigned short* __restrict__ WThi,
    const unsigned short* __restrict__ WTlo,
    const double* __restrict__ tokstats, const double* __restrict__ zrstats,
    const double* __restrict__ Vmat, const double* __restrict__ Cvec,
    const double* __restrict__ hbvec, const float* __restrict__ Wr2,
    float* __restrict__ logits)
{
    __shared__ struct {
        union {
            struct { float Af[128 * 32]; unsigned short Bh[128 * 32]; unsigned short Bl[128 * 32]; } g;
            struct { float Ht[64 * 133]; float W2[1024]; } e;
        } u;
        float mus[128], iss[128], Vs[128], Cs[128], hbs[128];
    } sm;

    const int tid = threadIdx.x;
    const int n0 = blockIdx.x * 128, tok0 = blockIdx.y * 128;
    const int b = tok0 >> 12;

    if (tid < 128) {
        int tok = tok0 + tid;
        double mu = (tokstats[(size_t)tok * 2] + zrstats[b * 2]) * (1.0 / 2048.0);
        double var = (tokstats[(size_t)tok * 2 + 1] + zrstats[b * 2 + 1]) * (1.0 / 2048.0) - mu * mu;
        sm.mus[tid] = (float)mu;
        sm.iss[tid] = (float)(1.0 / sqrt(var + 1e-5));
    } else {
        int n = tid - 128;
        sm.Vs[n] = (float)Vmat[(size_t)b * 1024 + n0 + n];
        sm.Cs[n] = (float)Cvec[n0 + n];
        sm.hbs[n] = (float)hbvec[n0 + n];
    }

    const int l = tid & 63, wid = tid >> 6;
    const int wm = wid >> 1, wn = wid & 1;
    const int lr = l & 15, q = l >> 4;

    const float* gA[4]; char* lA[4];
#pragma unroll
    for (int it = 0; it < 4; it++) {
        int c = it * 256 + tid;
        int m = c >> 3;
        int pg = (c & 7) ^ (m & 7);
        gA[it] = X + (size_t)(tok0 + m) * 1024 + pg * 4;
        lA[it] = (char*)sm.u.g.Af + c * 16;
    }
    const unsigned short *gBh[2], *gBl[2];
    char *lBh[2], *lBl[2];
#pragma unroll
    for (int it = 0; it < 2; it++) {
        int c = it * 256 + tid;
        int m = c >> 2;
        int p = (c & 3) ^ ((m >> 1) & 3);
        gBh[it] = WThi + (size_t)(n0 + m) * 1024 + p * 8;
        gBl[it] = WTlo + (size_t)(n0 + m) * 1024 + p * 8;
        lBh[it] = (char*)sm.u.g.Bh + c * 16;
        lBl[it] = (char*)sm.u.g.Bl + c * 16;
    }

    int boff[4], aoffr[4], s7a[4];
#pragma unroll
    for (int i = 0; i < 4; i++) {
        int rb = wn * 64 + i * 16 + lr;
        boff[i] = rb * 32 + ((q ^ ((rb >> 1) & 3)) << 3);
        int ra = wm * 64 + i * 16 + lr;
        aoffr[i] = ra * 32;
        s7a[i] = ra & 7;
    }

    f4v acc[4][4];
#pragma unroll
    for (int mi = 0; mi < 4; mi++)
#pragma unroll
        for (int ni = 0; ni < 4; ni++) acc[mi][ni] = (f4v){0.f, 0.f, 0.f, 0.f};

    for (int k0 = 0; k0 < 1024; k0 += 32) {
#pragma unroll
        for (int it = 0; it < 4; it++) gload16(gA[it] + k0, lA[it]);
#pragma unroll
        for (int it = 0; it < 2; it++) {
            gload16(gBh[it] + k0, lBh[it]);
            gload16(gBl[it] + k0, lBl[it]);
        }
        __syncthreads();

        s8v ah[4], al[4], bh4[4], bl4[4];
#pragma unroll
        for (int i = 0; i < 4; i++) {
            const float* Ab = sm.u.g.Af + aoffr[i];
            float4 f0 = *(const float4*)(Ab + ((((2 * q))     ^ s7a[i]) << 2));
            float4 f1 = *(const float4*)(Ab + ((((2 * q) | 1) ^ s7a[i]) << 2));
            unsigned u0 = __float_as_uint(f0.x), u1 = __float_as_uint(f0.y),
                     u2 = __float_as_uint(f0.z), u3 = __float_as_uint(f0.w),
                     u4 = __float_as_uint(f1.x), u5 = __float_as_uint(f1.y),
                     u6 = __float_as_uint(f1.z), u7 = __float_as_uint(f1.w);
            int4 hi4, lo4;
            hi4.x = (int)((u0 >> 16) | (u1 & 0xffff0000u));
            hi4.y = (int)((u2 >> 16) | (u3 & 0xffff0000u));
            hi4.z = (int)((u4 >> 16) | (u5 & 0xffff0000u));
            hi4.w = (int)((u6 >> 16) | (u7 & 0xffff0000u));
            float r0 = f0.x - __uint_as_float(u0 & 0xffff0000u);
            float r1 = f0.y - __uint_as_float(u1 & 0xffff0000u);
            float r2 = f0.z - __uint_as_float(u2 & 0xffff0000u);
            float r3 = f0.w - __uint_as_float(u3 & 0xffff0000u);
            float r4 = f1.x - __uint_as_float(u4 & 0xffff0000u);
            float r5 = f1.y - __uint_as_float(u5 & 0xffff0000u);
            float r6 = f1.z - __uint_as_float(u6 & 0xffff0000u);
            float r7 = f1.w - __uint_as_float(u7 & 0xffff0000u);
            lo4.x = (int)((__float_as_uint(r0) >> 16) | (__float_as_uint(r1) & 0xffff0000u));
            lo4.y = (int)((__float_as_uint(r2) >> 16) | (__float_as_uint(r3) & 0xffff0000u));
            lo4.z = (int)((__float_as_uint(r4) >> 16) | (__float_as_uint(r5) & 0xffff0000u));
            lo4.w = (int)((__float_as_uint(r6) >> 16) | (__float_as_uint(r7) & 0xffff0000u));
            ah[i] = __builtin_bit_cast(s8v, hi4);
            al[i] = __builtin_bit_cast(s8v, lo4);
            bh4[i] = *(const s8v*)(sm.u.g.Bh + boff[i]);
            bl4[i] = *(const s8v*)(sm.u.g.Bl + boff[i]);
        }
#pragma unroll
        for (int mi = 0; mi < 4; mi++)
#pragma unroll
            for (int ni = 0; ni < 4; ni++) {
                acc[mi][ni] = __builtin_amdgcn_mfma_f32_16x16x32_bf16(ah[mi], bh4[ni], acc[mi][ni], 0, 0, 0);
                acc[mi][ni] = __builtin_amdgcn_mfma_f32_16x16x32_bf16(al[mi], bh4[ni], acc[mi][ni], 0, 0, 0);
                acc[mi][ni] = __builtin_amdgcn_mfma_f32_16x16x32_bf16(ah[mi], bl4[ni], acc[mi][ni], 0, 0, 0);
            }
        __syncthreads();
    }

    float lacc[8];
#pragma unroll
    for (int h = 0; h < 8; h++) lacc[h] = 0.f;
    const int g2 = tid >> 7, mrow = tid & 127;

#pragma unroll
    for (int p = 0; p < 2; p++) {
#pragma unroll
        for (int nh = 0; nh < 2; nh++) {
            int ni = 2 * p + nh;
            int n = wn * 64 + ni * 16 + lr;
            int jl = wn * 32 + nh * 16 + lr;
            float Vnx = sm.Vs[n], Cnx = sm.Cs[n], hbnx = sm.hbs[n];
#pragma unroll
            for (int mi = 0; mi < 4; mi++) {
#pragma unroll
                for (int rr = 0; rr < 4; rr++) {
                    int m = wm * 64 + mi * 16 + q * 4 + rr;
                    float h = sm.iss[m] * (acc[mi][ni][rr] + Vnx - sm.mus[m] * Cnx) + hbnx;
                    sm.u.e.Ht[jl * 133 + m] = geluf(h);
                }
            }
        }
        for (int idx = tid; idx < 1024; idx += 256) {
            int jl = idx >> 4;
            int n = ((jl >> 5) << 6) + p * 32 + (jl & 31);
            sm.u.e.W2[idx] = Wr2[(size_t)(n0 + n) * 16 + (idx & 15)];
        }
        __syncthreads();
#pragma unroll 8
        for (int jl = 0; jl < 64; jl++) {
            float x = sm.u.e.Ht[jl * 133 + mrow];
#pragma unroll
            for (int h = 0; h < 8; h++) lacc[h] += x * sm.u.e.W2[jl * 16 + g2 * 8 + h];
        }
        __syncthreads();
    }
#pragma unroll
    for (int h = 0; h < 8; h++)
        atomicAdd(&logits[(size_t)(tok0 + mrow) * 16 + g2 * 8 + h], lacc[h]);
}

// ---------------------------------------------------------------------------
// 10) softmax + top2 + renorm -> fp32 output; flag tokens with small
//     v(2)-v(3) margin for exact recompute.
// ---------------------------------------------------------------------------
#define FLAG_CAP 16384
__global__ __launch_bounds__(256) void softflag_kernel(
    const float* __restrict__ logits, const float* __restrict__ br2,
    float* __restrict__ out, int* __restrict__ cnt, int* __restrict__ flagged)
{
    int t = blockIdx.x * 256 + threadIdx.x;
    float v[16];
    const float4* lp = (const float4*)(logits + (size_t)t * 16);
    float4 a0 = lp[0], a1 = lp[1], a2 = lp[2], a3 = lp[3];
    v[0] = a0.x; v[1] = a0.y; v[2] = a0.z; v[3] = a0.w;
    v[4] = a1.x; v[5] = a1.y; v[6] = a1.z; v[7] = a1.w;
    v[8] = a2.x; v[9] = a2.y; v[10] = a2.z; v[11] = a2.w;
    v[12] = a3.x; v[13] = a3.y; v[14] = a3.z; v[15] = a3.w;
#pragma unroll
    for (int h = 0; h < 16; h++) v[h] += br2[h];
    int i1 = 0; float b1 = v[0];
#pragma unroll
    for (int h = 1; h < 16; h++) if (v[h] > b1) { b1 = v[h]; i1 = h; }
    int i2 = -1; float b2 = -3.4e38f;
#pragma unroll
    for (int h = 0; h < 16; h++) if (h != i1 && v[h] > b2) { b2 = v[h]; i2 = h; }
    float b3 = -3.4e38f;
#pragma unroll
    for (int h = 0; h < 16; h++) if (h != i1 && h != i2 && v[h] > b3) b3 = v[h];
    float mx = b1;
    float e1 = expf(b1 - mx), e2 = expf(b2 - mx);
    float s = 0.f;
#pragma unroll
    for (int h = 0; h < 16; h++) s += expf(v[h] - mx);
    float a1v = e1 / s, a2v = e2 / s;
    float den = fmaxf(a1v + a2v, 1e-12f);
    float r1 = a1v / den, r2 = a2v / den;
    float o[16];
#pragma unroll
    for (int h = 0; h < 16; h++) o[h] = (h == i1 ? r1 : (h == i2 ? r2 : 0.f));
    float4* op = (float4*)(out + (size_t)t * 16);
    op[0] = make_float4(o[0], o[1], o[2], o[3]);
    op[1] = make_float4(o[4], o[5], o[6], o[7]);
    op[2] = make_float4(o[8], o[9], o[10], o[11]);
    op[3] = make_float4(o[12], o[13], o[14], o[15]);
    if (b2 - b3 < 1e-3f) {
        int slot = atomicAdd(cnt, 1);
        if (slot < FLAG_CAP) flagged[slot] = t;
    }
}

// ---------------------------------------------------------------------------
// 11) per-flagged-token double LN stats
// ---------------------------------------------------------------------------
__global__ void flagstat_kernel(const float* __restrict__ X,
                                const double* __restrict__ zrstats,
                                const int* __restrict__ cnt,
                                const int* __restrict__ flagged,
                                double* __restrict__ fstats)
{
    int n = cnt[0]; if (n > FLAG_CAP) n = FLAG_CAP;
    int s = blockIdx.x;
    if (s >= n) return;
    int tok = flagged[s], b = tok >> 12;
    int l = threadIdx.x;
    double s1 = 0.0, s2 = 0.0;
#pragma unroll
    for (int m = 0; m < 16; m++) {
        double x = (double)X[(size_t)tok * 1024 + l + 64 * m];
        s1 += x; s2 += x * x;
    }
#pragma unroll
    for (int off = 32; off >= 1; off >>= 1) {
        s1 += __shfl_xor(s1, off, 64);
        s2 += __shfl_xor(s2, off, 64);
    }
    if (l == 0) {
        double mu = (s1 + zrstats[b * 2]) * (1.0 / 2048.0);
        double var = (s2 + zrstats[b * 2 + 1]) * (1.0 / 2048.0) - mu * mu;
        fstats[s * 2] = mu;
        fstats[s * 2 + 1] = 1.0 / sqrt(var + 1e-5);
    }
}

// ---------------------------------------------------------------------------
// 12) exact double recompute of logits for flagged tokens — token-parallel.
// ---------------------------------------------------------------------------
__global__ __launch_bounds__(256) void exact2_kernel(
    const float* __restrict__ X, const float* __restrict__ Wr1,
    const float* __restrict__ gr, const double* __restrict__ zv,
    const double* __restrict__ Cvec, const double* __restrict__ hbvec,
    const float* __restrict__ Wr2,
    const int* __restrict__ cnt, const int* __restrict__ flagged,
    const double* __restrict__ fstats, double* __restrict__ exlog)
{
    int n = cnt[0]; if (n > FLAG_CAP) n = FLAG_CAP;
    const int c = blockIdx.y;
    if (c * 16 >= n) return;
    int nt = n - c * 16; if (nt > 16) nt = 16;

    __shared__ double aS[16][65];
    __shared__ double gS[16][129];
    __shared__ double mus[16], iss[16];
    __shared__ int toks[16];

    const int tid = threadIdx.x;
    const int j0 = blockIdx.x * 128;
    const int jl = tid & 127;
    const int j = j0 + jl;
    const int tg = (tid >> 7) * 8;

    if (tid < 16) {
        if (tid < nt) {
            toks[tid] = flagged[c * 16 + tid];
            mus[tid] = fstats[(size_t)(c * 16 + tid) * 2];
            iss[tid] = fstats[(size_t)(c * 16 + tid) * 2 + 1];
        } else {
            toks[tid] = 0; mus[tid] = 0.0; iss[tid] = 0.0;
        }
    }
    __syncthreads();

    double acc[8];
#pragma unroll
    for (int t = 0; t < 8; t++) acc[t] = 0.0;

    for (int i0 = 0; i0 < 2048; i0 += 64) {
        for (int idx = tid; idx < 1024; idx += 256) {
            int t = idx >> 6, ii = idx & 63, i = i0 + ii;
            double v = 0.0;
            if (t < nt) {
                int tok = toks[t];
                if (i < 1024)
                    v = (double)X[(size_t)tok * 1024 + i] * (double)gr[i];
                else
                    v = zv[(size_t)(tok >> 12) * 1024 + (i - 1024)];
            }
            aS[t][ii] = v;
        }
        __syncthreads();
#pragma unroll 8
        for (int ii = 0; ii < 64; ii++) {
            double wv = (double)Wr1[(size_t)(i0 + ii) * 1024 + j];
#pragma unroll
            for (int t = 0; t < 8; t++) acc[t] += aS[tg + t][ii] * wv;
        }
        __syncthreads();
    }

    {
        double Cj = Cvec[j], hbj = hbvec[j];
#pragma unroll
        for (int t = 0; t < 8; t++) {
            double pre = iss[tg + t] * (acc[t] - mus[tg + t] * Cj) + hbj;
            gS[tg + t][jl] = gelud(pre);
        }
    }
    __syncthreads();

    {
        int t = tid >> 4, h = tid & 15;
        double p = 0.0;
#pragma unroll 8
        for (int j2 = 0; j2 < 128; j2++)
            p += gS[t][j2] * (double)Wr2[(size_t)(j0 + j2) * 16 + h];
        if (t < nt)
            atomicAdd(&exlog[(size_t)(c * 16 + t) * 16 + h], p);
    }
}

// ---------------------------------------------------------------------------
// 13) fix kernel: double softmax+top2 for flagged tokens, overwrite out rows
// ---------------------------------------------------------------------------
__global__ __launch_bounds__(256) void fix_kernel(
    const double* __restrict__ exlog, const float* __restrict__ br2,
    const int* __restrict__ cnt, const int* __restrict__ flagged,
    float* __restrict__ out)
{
    int s = blockIdx.x * 256 + threadIdx.x;
    int n = cnt[0]; if (n > FLAG_CAP) n = FLAG_CAP;
    if (s >= n) return;
    int tok = flagged[s];
    double v[16];
#pragma unroll
    for (int h = 0; h < 16; h++) v[h] = exlog[(size_t)s * 16 + h] + (double)br2[h];
    int i1 = 0; double b1 = v[0];
#pragma unroll
    for (int h = 1; h < 16; h++) if (v[h] > b1) { b1 = v[h]; i1 = h; }
    int i2 = -1; double b2 = -1e300;
#pragma unroll
    for (int h = 0; h < 16; h++) if (h != i1 && v[h] > b2) { b2 = v[h]; i2 = h; }
    double ssum = 0.0;
#pragma unroll
    for (int h = 0; h < 16; h++) ssum += exp(v[h] - b1);
    double a1v = exp(b1 - b1) / ssum, a2v = exp(b2 - b1) / ssum;
    double den = a1v + a2v; if (den < 1e-12) den = 1e-12;
    float r1 = (float)(a1v / den), r2 = (float)(a2v / den);
#pragma unroll
    for (int h = 0; h < 16; h++)
        out[(size_t)tok * 16 + h] = (h == i1 ? r1 : (h == i2 ? r2 : 0.f));
}

// ---------------------------------------------------------------------------
// launch
// ---------------------------------------------------------------------------
extern "C" void kernel_launch(void* const* d_in, const int* in_sizes, int n_in,
                              void* d_out, int out_size, void* d_ws, size_t ws_size,
                              hipStream_t stream)
{
    const float* X      = (const float*)d_in[0];
    const float* z_in   = (const float*)d_in[1];
    const int*   stepi  = (const int*)d_in[2];
    const float* g_pool = (const float*)d_in[3];
    const float* b_pool = (const float*)d_in[4];
    const float* W_inp  = (const float*)d_in[5];
    const float* b_inp  = (const float*)d_in[6];
    const float* Wt1    = (const float*)d_in[7];
    const float* bt1    = (const float*)d_in[8];
    const float* Wt2    = (const float*)d_in[9];
    const float* bt2    = (const float*)d_in[10];
    const float* Wc1    = (const float*)d_in[11];
    const float* bc1    = (const float*)d_in[12];
    const float* Wc2    = (const float*)d_in[13];
    const float* bc2    = (const float*)d_in[14];
    const float* W_mod  = (const float*)d_in[15];
    const float* b_mod  = (const float*)d_in[16];
    const float* Wm1    = (const float*)d_in[17];
    const float* bm1    = (const float*)d_in[18];
    const float* Wm2    = (const float*)d_in[19];
    const float* bm2    = (const float*)d_in[20];
    const float* Wf     = (const float*)d_in[21];
    const float* bf_b   = (const float*)d_in[22];
    const float* gz     = (const float*)d_in[23];
    const float* bz     = (const float*)d_in[24];
    const float* gr     = (const float*)d_in[25];
    const float* br     = (const float*)d_in[26];
    const float* Wr1    = (const float*)d_in[27];
    const float* br1    = (const float*)d_in[28];
    const float* Wr2    = (const float*)d_in[29];
    const float* br2    = (const float*)d_in[30];

    char* wsb = (char*)d_ws;
    // ---- workspace layout (byte offsets) ----
    const size_t OB_LOGA  = 0;         // float[524288]      2,097,152
    const size_t OB_EXLOG = 2097152;   // double[16384*16]   2,097,152
    const size_t OB_CNT   = 4194304;   // int[16]            64
    const size_t OB_FLAG  = 4194368;   // int[16384]         65,536
    const size_t OB_MACC  = 4259904;   // double[8192]       65,536
    const size_t OB_XCTRL = 4325440;   // double[8192]
    const size_t OB_TH1   = 4390976;   // double[4096]
    const size_t OB_TEMB  = 4423744;   // double[1024]
    const size_t OB_CH    = 4431936;   // double[8192]
    const size_t OB_COND  = 4497472;   // double[8192]
    const size_t OB_MOD   = 4563008;   // double[2*32768]
    const size_t OB_H1    = 5087296;   // double[2*32768]
    const size_t OB_H2    = 5611584;   // double[2*8192]
    const size_t OB_ZFPRE = 5742656;   // double[8192]
    const size_t OB_V     = 5808192;   // double[8192]
    const size_t OB_TOKST = 5873728;   // double[65536]
    const size_t OB_FSTAT = 6398016;   // double[32768]
    const size_t OB_EMB   = 6660160;   // double[1024]
    const size_t OB_ZB0   = 6668352;   // double[8192]
    const size_t OB_ZB1   = 6733888;   // double[8192]
    const size_t OB_ZST   = 6799424;   // double[16]
    const size_t OB_ZRST  = 6799552;   // double[16]
    const size_t OB_ZV    = 6799680;   // double[8192]
    const size_t OB_CVEC  = 6865216;   // double[1024]   (zeroed: colsum atomics)
    const size_t OB_HB    = 6873408;   // double[1024]   (zeroed: colsum atomics)
    const size_t ZEND     = 6881600;   // end of zeroed region
    const size_t OB_WTHI  = 6881600;   // ushort[1M]         2,097,152
    const size_t OB_WTLO  = 8978752;   // ushort[1M]         2,097,152
    const size_t OB_XH    = 11075904;  // ushort[32768*1024] 67,108,864
    const size_t OB_XL    = 78184768;  // ushort[32768*1024] 67,108,864
    const size_t WS_BIG   = 145293632; // required for bf16-A fast path

    unsigned short* WThi = (unsigned short*)(wsb + OB_WTHI);
    unsigned short* WTlo = (unsigned short*)(wsb + OB_WTLO);
    int* cntp  = (int*)(wsb + OB_CNT);
    int* flagp = (int*)(wsb + OB_FLAG);

    const bool big = ws_size >= WS_BIG;
    unsigned short* XHp = big ? (unsigned short*)(wsb + OB_XH) : nullptr;
    unsigned short* XLp = big ? (unsigned short*)(wsb + OB_XL) : nullptr;

    hipMemsetAsync(d_ws, 0, ZEND, stream);

    pool_kernel<<<dim3(64, 8), 256, 0, stream>>>(X, (double*)(wsb + OB_MACC),
                                                 (double*)(wsb + OB_TOKST), XHp, XLp);
    prep_kernel<<<1, 256, 0, stream>>>(stepi, z_in, (double*)(wsb + OB_EMB), (double*)(wsb + OB_ZB0));
    prepw_kernel<<<dim3(16, 16), 256, 0, stream>>>(Wr1, gr, WThi, WTlo);
    colsum_kernel<<<dim3(4, 16), 256, 0, stream>>>(Wr1, gr, br, br1,
        (double*)(wsb + OB_CVEC), (double*)(wsb + OB_HB));

    // x_ctrl_pre = g @ W_inp
    gemvd_kernel<1, 8><<<dim3(4, 16), 256, 0, stream>>>(W_inp, 1024, 1024, 64, 1024,
        (double*)(wsb + OB_MACC), nullptr, nullptr, g_pool, b_pool, (double*)(wsb + OB_XCTRL));
    // th1_pre = emb @ Wt1
    gemvd_kernel<0, 1><<<dim3(16, 16), 256, 0, stream>>>(Wt1, 1024, 4096, 64, 1024,
        (double*)(wsb + OB_EMB), nullptr, nullptr, nullptr, nullptr, (double*)(wsb + OB_TH1));
    // t_embed_pre = gelu(th1_pre + bt1) @ Wt2
    gemvd_kernel<2, 1><<<dim3(4, 16), 256, 0, stream>>>(Wt2, 4096, 1024, 256, 4096,
        (double*)(wsb + OB_TH1), nullptr, nullptr, bt1, nullptr, (double*)(wsb + OB_TEMB));
    // ch_pre = concat(x_ctrl_pre+b_inp, t_embed_pre+bt2) @ Wc1
    gemvd_kernel<4, 8><<<dim3(4, 16), 256, 0, stream>>>(Wc1, 2048, 1024, 128, 1024,
        (double*)(wsb + OB_XCTRL), (double*)(wsb + OB_TEMB), nullptr, b_inp, bt2, (double*)(wsb + OB_CH));
    // cond_pre = gelu(ch_pre + bc1) @ Wc2
    gemvd_kernel<2, 8><<<dim3(4, 16), 256, 0, stream>>>(Wc2, 1024, 1024, 64, 1024,
        (double*)(wsb + OB_CH), nullptr, nullptr, bc1, nullptr, (double*)(wsb + OB_COND));

    stats8_kernel<<<8, 256, 0, stream>>>((double*)(wsb + OB_ZB0), (double*)(wsb + OB_ZST));

    for (int ll = 0; ll < 2; ll++) {
        double* zcur  = (double*)(wsb + (ll == 0 ? OB_ZB0 : OB_ZB1));
        double* znext = (double*)(wsb + (ll == 0 ? OB_ZB1 : OB_ZB0));
        double* modp  = (double*)(wsb + OB_MOD) + (size_t)ll * 32768;
        double* h1p   = (double*)(wsb + OB_H1) + (size_t)ll * 32768;
        double* h2p   = (double*)(wsb + OB_H2) + (size_t)ll * 8192;
        gemvd_kernel<2, 8><<<dim3(16, 16), 256, 0, stream>>>(W_mod + (size_t)ll * 4194304,
            1024, 4096, 64, 1024, (double*)(wsb + OB_COND), nullptr, nullptr, bc2, nullptr, modp);
        gemvd_kernel<3, 8><<<dim3(16, 16), 256, 0, stream>>>(Wm1 + (size_t)ll * 4194304,
            1024, 4096, 64, 1024, zcur, (double*)(wsb + OB_ZST), modp, b_mod + ll * 4096, nullptr, h1p);
        gemvd_kernel<2, 8><<<dim3(4, 16), 256, 0, stream>>>(Wm2 + (size_t)ll * 4194304,
            4096, 1024, 256, 4096, h1p, nullptr, nullptr, bm1 + ll * 4096, nullptr, h2p);
        resid_kernel<<<8, 256, 0, stream>>>(zcur, h2p, bm2 + ll * 1024, modp,
                                            b_mod + ll * 4096, znext, (double*)(wsb + OB_ZST));
    }

    // zf_pre = z @ Wf
    gemvd_kernel<0, 8><<<dim3(4, 16), 256, 0, stream>>>(Wf, 1024, 1024, 64, 1024,
        (double*)(wsb + OB_ZB0), nullptr, nullptr, nullptr, nullptr, (double*)(wsb + OB_ZFPRE));
    zfinal_kernel<<<8, 256, 0, stream>>>((double*)(wsb + OB_ZFPRE), bf_b, gz, bz, gr,
                                         (double*)(wsb + OB_ZV), (double*)(wsb + OB_ZRST));
    // V = zv @ Wr1[1024:,:]
    gemvd_kernel<0, 8><<<dim3(4, 16), 256, 0, stream>>>(Wr1 + (size_t)1024 * 1024,
        1024, 1024, 64, 1024, (double*)(wsb + OB_ZV), nullptr, nullptr, nullptr, nullptr,
        (double*)(wsb + OB_V));

    if (big) {
        router4_kernel<<<2048, 256, 0, stream>>>(XHp, XLp, WThi, WTlo,
            (double*)(wsb + OB_TOKST), (double*)(wsb + OB_ZRST), (double*)(wsb + OB_V),
            (double*)(wsb + OB_CVEC), (double*)(wsb + OB_HB), Wr2, (float*)(wsb + OB_LOGA));
    } else {
        router_kernel<<<dim3(8, 256), 256, 0, stream>>>(X, WThi, WTlo,
            (double*)(wsb + OB_TOKST), (double*)(wsb + OB_ZRST), (double*)(wsb + OB_V),
            (double*)(wsb + OB_CVEC), (double*)(wsb + OB_HB), Wr2, (float*)(wsb + OB_LOGA));
    }

    softflag_kernel<<<128, 256, 0, stream>>>((float*)(wsb + OB_LOGA), br2,
        (float*)d_out, cntp, flagp);
    flagstat_kernel<<<16384, 64, 0, stream>>>(X, (double*)(wsb + OB_ZRST), cntp, flagp,
        (double*)(wsb + OB_FSTAT));
    exact2_kernel<<<dim3(8, 1024), 256, 0, stream>>>(X, Wr1, gr, (double*)(wsb + OB_ZV),
        (double*)(wsb + OB_CVEC), (double*)(wsb + OB_HB), Wr2, cntp, flagp,
        (double*)(wsb + OB_FSTAT), (double*)(wsb + OB_EXLOG));
    fix_kernel<<<64, 256, 0, stream>>>((double*)(wsb + OB_EXLOG), br2, cntp, flagp,
        (float*)d_out);
}